// Round 1
// baseline (1363.124 us; speedup 1.0000x reference)
//
#include <hip/hip_runtime.h>

#define N_NODES 50000
#define E_EDGES 800000
#define HID 128          // H*C = 4*32
#define LRELU 0.2f
#define LN_EPS 1e-5f

// ---------------------------------------------------------------------------
// GEMM: C[:, z*128 + col] = A[N,128] @ Wz[128,128], C row stride 384.
// grid = (2, ceil(N/64), 3); block = 256. 64x64 tile, 4x4 per thread.
// ---------------------------------------------------------------------------
__global__ __launch_bounds__(256) void gemm3_kernel(
    const float* __restrict__ A,
    const float* __restrict__ W0, const float* __restrict__ W1,
    const float* __restrict__ W2,
    float* __restrict__ C, int n)
{
    const int z = blockIdx.z;
    const float* __restrict__ W = (z == 0) ? W0 : ((z == 1) ? W1 : W2);
    const int row0 = blockIdx.y * 64;
    const int col0 = blockIdx.x * 64;   // within [0,128)

    __shared__ float As[32][65];  // [k][m]
    __shared__ float Bs[32][65];  // [k][c]

    const int tid = threadIdx.x;
    const int tx = tid & 15;      // 0..15 -> 4 cols each
    const int ty = tid >> 4;      // 0..15 -> 4 rows each

    float acc[4][4] = {};

    for (int kk = 0; kk < 128; kk += 32) {
        // Load A tile: 64 rows x 32 k. 512 float4, 2 per thread.
        #pragma unroll
        for (int i = 0; i < 2; ++i) {
            int idx = tid + i * 256;
            int r  = idx >> 3;          // 0..63
            int k4 = idx & 7;           // 0..7
            int grow = row0 + r;
            float4 v = make_float4(0.f, 0.f, 0.f, 0.f);
            if (grow < n)
                v = *(const float4*)(A + (size_t)grow * 128 + kk + k4 * 4);
            As[k4 * 4 + 0][r] = v.x;
            As[k4 * 4 + 1][r] = v.y;
            As[k4 * 4 + 2][r] = v.z;
            As[k4 * 4 + 3][r] = v.w;
        }
        // Load B tile: 32 k x 64 cols. 512 float4, 2 per thread.
        #pragma unroll
        for (int i = 0; i < 2; ++i) {
            int idx = tid + i * 256;
            int kr = idx >> 4;          // 0..31
            int c4 = idx & 15;          // 0..15
            float4 v = *(const float4*)(W + (size_t)(kk + kr) * 128 + col0 + c4 * 4);
            Bs[kr][c4 * 4 + 0] = v.x;
            Bs[kr][c4 * 4 + 1] = v.y;
            Bs[kr][c4 * 4 + 2] = v.z;
            Bs[kr][c4 * 4 + 3] = v.w;
        }
        __syncthreads();
        #pragma unroll
        for (int k = 0; k < 32; ++k) {
            float4 a4 = *(const float4*)&As[k][ty * 4];
            float4 b4 = *(const float4*)&Bs[k][tx * 4];
            float a[4] = {a4.x, a4.y, a4.z, a4.w};
            float b[4] = {b4.x, b4.y, b4.z, b4.w};
            #pragma unroll
            for (int i = 0; i < 4; ++i)
                #pragma unroll
                for (int j = 0; j < 4; ++j)
                    acc[i][j] += a[i] * b[j];
        }
        __syncthreads();
    }

    const int cbase = z * 128 + col0 + tx * 4;
    #pragma unroll
    for (int i = 0; i < 4; ++i) {
        int r = row0 + ty * 4 + i;
        if (r < n) {
            float4 v = make_float4(acc[i][0], acc[i][1], acc[i][2], acc[i][3]);
            *(float4*)(C + (size_t)r * 384 + cbase) = v;
        }
    }
}

// ---------------------------------------------------------------------------
// Attention scores: a_s[n,h] = sum_c xs[n,h,c]*att_src[h,c]; same for a_d.
// One thread per (node, head).
// ---------------------------------------------------------------------------
__global__ __launch_bounds__(256) void attn_scores_kernel(
    const float* __restrict__ buf,       // [n,384] xs|xd|skip
    const float* __restrict__ att_src,   // [128]
    const float* __restrict__ att_dst,
    float* __restrict__ a_s, float* __restrict__ a_d, int n)
{
    int idx = blockIdx.x * blockDim.x + threadIdx.x;
    if (idx >= n * 4) return;
    int node = idx >> 2, h = idx & 3;
    const float* xs = buf + (size_t)node * 384 + h * 32;
    const float* xd = xs + 128;
    float s = 0.f, d = 0.f;
    #pragma unroll
    for (int c4 = 0; c4 < 8; ++c4) {
        float4 vs  = *(const float4*)(xs + c4 * 4);
        float4 vd  = *(const float4*)(xd + c4 * 4);
        float4 as4 = *(const float4*)(att_src + h * 32 + c4 * 4);
        float4 ad4 = *(const float4*)(att_dst + h * 32 + c4 * 4);
        s += vs.x * as4.x + vs.y * as4.y + vs.z * as4.z + vs.w * as4.w;
        d += vd.x * ad4.x + vd.y * ad4.y + vd.z * ad4.z + vd.w * ad4.w;
    }
    a_s[idx] = s;
    a_d[idx] = d;
}

// ---------------------------------------------------------------------------
// Edge pass 1: ee = exp(leaky_relu(a_s[src]+a_d[dst])); denom[dst] += ee.
// One thread per edge (all 4 heads). Softmax shift dropped (shift-invariant).
// ---------------------------------------------------------------------------
__global__ __launch_bounds__(256) void edge_softmax_kernel(
    const int* __restrict__ src, const int* __restrict__ dst,
    const float* __restrict__ a_s, const float* __restrict__ a_d,
    float* __restrict__ ee, float* __restrict__ denom, int e)
{
    int i = blockIdx.x * blockDim.x + threadIdx.x;
    if (i >= e) return;
    int s = src[i], d = dst[i];
    float4 as = *(const float4*)(a_s + (size_t)s * 4);
    float4 ad = *(const float4*)(a_d + (size_t)d * 4);
    float v0 = as.x + ad.x, v1 = as.y + ad.y, v2 = as.z + ad.z, v3 = as.w + ad.w;
    v0 = (v0 > 0.f) ? v0 : LRELU * v0;
    v1 = (v1 > 0.f) ? v1 : LRELU * v1;
    v2 = (v2 > 0.f) ? v2 : LRELU * v2;
    v3 = (v3 > 0.f) ? v3 : LRELU * v3;
    float e0 = __expf(v0), e1 = __expf(v1), e2 = __expf(v2), e3 = __expf(v3);
    *(float4*)(ee + (size_t)i * 4) = make_float4(e0, e1, e2, e3);
    atomicAdd(&denom[(size_t)d * 4 + 0], e0);
    atomicAdd(&denom[(size_t)d * 4 + 1], e1);
    atomicAdd(&denom[(size_t)d * 4 + 2], e2);
    atomicAdd(&denom[(size_t)d * 4 + 3], e3);
}

// ---------------------------------------------------------------------------
// Edge pass 2: gat[dst, h*32+c] += xs[src, h*32+c] * ee/(denom[dst]+1e-16).
// 32 threads per edge; thread g handles channel g of each of the 4 heads.
// ---------------------------------------------------------------------------
__global__ __launch_bounds__(256) void edge_aggregate_kernel(
    const int* __restrict__ src, const int* __restrict__ dst,
    const float* __restrict__ buf,       // xs at cols 0..127, row stride 384
    const float* __restrict__ ee, const float* __restrict__ denom,
    float* __restrict__ gat, int e)
{
    int gidx = blockIdx.x * blockDim.x + threadIdx.x;
    int edge = gidx >> 5;
    int g = gidx & 31;
    if (edge >= e) return;
    int s = src[edge], d = dst[edge];
    float4 eev = *(const float4*)(ee + (size_t)edge * 4);
    float4 den = *(const float4*)(denom + (size_t)d * 4);
    float al0 = eev.x / (den.x + 1e-16f);
    float al1 = eev.y / (den.y + 1e-16f);
    float al2 = eev.z / (den.z + 1e-16f);
    float al3 = eev.w / (den.w + 1e-16f);
    const float* xs = buf + (size_t)s * 384;
    float* go = gat + (size_t)d * 128;
    atomicAdd(go + g,      xs[g]      * al0);
    atomicAdd(go + 32 + g, xs[32 + g] * al1);
    atomicAdd(go + 64 + g, xs[64 + g] * al2);
    atomicAdd(go + 96 + g, xs[96 + g] * al3);
}

// ---------------------------------------------------------------------------
// h = relu(LN(gat + b1 + skip + bl1) * gamma + beta). One wave per node.
// ---------------------------------------------------------------------------
__global__ __launch_bounds__(256) void ln_relu_kernel(
    const float* __restrict__ gat, const float* __restrict__ buf,
    const float* __restrict__ b1, const float* __restrict__ bl1,
    const float* __restrict__ gamma, const float* __restrict__ beta,
    float* __restrict__ h, int n)
{
    int wave = (blockIdx.x * blockDim.x + threadIdx.x) >> 6;
    int lane = threadIdx.x & 63;
    if (wave >= n) return;
    const float* g0 = gat + (size_t)wave * 128;
    const float* sk = buf + (size_t)wave * 384 + 256;
    float v0 = g0[lane]      + sk[lane]      + b1[lane]      + bl1[lane];
    float v1 = g0[lane + 64] + sk[lane + 64] + b1[lane + 64] + bl1[lane + 64];
    float sum = v0 + v1, sq = v0 * v0 + v1 * v1;
    #pragma unroll
    for (int off = 32; off; off >>= 1) {
        sum += __shfl_xor(sum, off);
        sq  += __shfl_xor(sq, off);
    }
    float mu = sum * (1.f / 128.f);
    float var = sq * (1.f / 128.f) - mu * mu;
    float rs = rsqrtf(var + LN_EPS);
    float o0 = (v0 - mu) * rs * gamma[lane]      + beta[lane];
    float o1 = (v1 - mu) * rs * gamma[lane + 64] + beta[lane + 64];
    h[(size_t)wave * 128 + lane]      = fmaxf(o0, 0.f);
    h[(size_t)wave * 128 + 64 + lane] = fmaxf(o1, 0.f);
}

// ---------------------------------------------------------------------------
// out = gat2 + b2 + skip2 + bl2
// ---------------------------------------------------------------------------
__global__ __launch_bounds__(256) void final_add_kernel(
    const float* __restrict__ gat, const float* __restrict__ buf,
    const float* __restrict__ b2, const float* __restrict__ bl2,
    float* __restrict__ out, int n)
{
    int idx = blockIdx.x * blockDim.x + threadIdx.x;
    if (idx >= n * 128) return;
    int node = idx >> 7, c = idx & 127;
    out[idx] = gat[idx] + buf[(size_t)node * 384 + 256 + c] + b2[c] + bl2[c];
}

extern "C" void kernel_launch(void* const* d_in, const int* in_sizes, int n_in,
                              void* d_out, int out_size, void* d_ws, size_t ws_size,
                              hipStream_t stream) {
    const float* x       = (const float*)d_in[0];
    const int*   ei      = (const int*)d_in[1];
    const int*   src     = ei;
    const int*   dst     = ei + E_EDGES;
    const float* W1_src  = (const float*)d_in[2];
    const float* W1_dst  = (const float*)d_in[3];
    const float* att1_s  = (const float*)d_in[4];
    const float* att1_d  = (const float*)d_in[5];
    const float* b1      = (const float*)d_in[6];
    const float* Wl1     = (const float*)d_in[7];
    const float* bl1     = (const float*)d_in[8];
    const float* gamma   = (const float*)d_in[9];
    const float* beta    = (const float*)d_in[10];
    const float* W2_src  = (const float*)d_in[11];
    const float* W2_dst  = (const float*)d_in[12];
    const float* att2_s  = (const float*)d_in[13];
    const float* att2_d  = (const float*)d_in[14];
    const float* b2      = (const float*)d_in[15];
    const float* Wl2     = (const float*)d_in[16];
    const float* bl2     = (const float*)d_in[17];
    float* out = (float*)d_out;

    float* buf   = (float*)d_ws;                        // N*384
    float* a_s   = buf   + (size_t)N_NODES * 384;       // N*4
    float* a_d   = a_s   + (size_t)N_NODES * 4;         // N*4
    float* denom = a_d   + (size_t)N_NODES * 4;         // N*4
    float* eebuf = denom + (size_t)N_NODES * 4;         // E*4
    float* gat   = eebuf + (size_t)E_EDGES * 4;         // N*128
    float* hbuf  = gat   + (size_t)N_NODES * 128;       // N*128

    dim3 ggrid(2, (N_NODES + 63) / 64, 3);
    int attn_grid  = (N_NODES * 4 + 255) / 256;
    int e1_grid    = (E_EDGES + 255) / 256;
    int e2_grid    = (int)(((size_t)E_EDGES * 32 + 255) / 256);
    int ln_grid    = (N_NODES + 3) / 4;
    int final_grid = (N_NODES * 128 + 255) / 256;

    // -------- layer 1 --------
    hipMemsetAsync(denom, 0, (size_t)N_NODES * 4 * sizeof(float), stream);
    hipMemsetAsync(gat,   0, (size_t)N_NODES * 128 * sizeof(float), stream);
    gemm3_kernel<<<ggrid, 256, 0, stream>>>(x, W1_src, W1_dst, Wl1, buf, N_NODES);
    attn_scores_kernel<<<attn_grid, 256, 0, stream>>>(buf, att1_s, att1_d, a_s, a_d, N_NODES);
    edge_softmax_kernel<<<e1_grid, 256, 0, stream>>>(src, dst, a_s, a_d, eebuf, denom, E_EDGES);
    edge_aggregate_kernel<<<e2_grid, 256, 0, stream>>>(src, dst, buf, eebuf, denom, gat, E_EDGES);
    ln_relu_kernel<<<ln_grid, 256, 0, stream>>>(gat, buf, b1, bl1, gamma, beta, hbuf, N_NODES);

    // -------- layer 2 --------
    hipMemsetAsync(denom, 0, (size_t)N_NODES * 4 * sizeof(float), stream);
    hipMemsetAsync(gat,   0, (size_t)N_NODES * 128 * sizeof(float), stream);
    gemm3_kernel<<<ggrid, 256, 0, stream>>>(hbuf, W2_src, W2_dst, Wl2, buf, N_NODES);
    attn_scores_kernel<<<attn_grid, 256, 0, stream>>>(buf, att2_s, att2_d, a_s, a_d, N_NODES);
    edge_softmax_kernel<<<e1_grid, 256, 0, stream>>>(src, dst, a_s, a_d, eebuf, denom, E_EDGES);
    edge_aggregate_kernel<<<e2_grid, 256, 0, stream>>>(src, dst, buf, eebuf, denom, gat, E_EDGES);
    final_add_kernel<<<final_grid, 256, 0, stream>>>(gat, buf, b2, bl2, out, N_NODES);
}

// Round 2
// 718.040 us; speedup vs baseline: 1.8984x; 1.8984x over previous
//
#include <hip/hip_runtime.h>

#define N_NODES 50000
#define E_EDGES 800000
#define LRELU 0.2f
#define LN_EPS 1e-5f

// ---------------------------------------------------------------------------
// GEMM: C[:, z*128 + col] = A[N,128] @ Wz[128,128], C row stride 384.
// grid = (2, ceil(N/64), 3); block = 256. 64x64 tile, 4x4 per thread.
// ---------------------------------------------------------------------------
__global__ __launch_bounds__(256) void gemm3_kernel(
    const float* __restrict__ A,
    const float* __restrict__ W0, const float* __restrict__ W1,
    const float* __restrict__ W2,
    float* __restrict__ C, int n)
{
    const int z = blockIdx.z;
    const float* __restrict__ W = (z == 0) ? W0 : ((z == 1) ? W1 : W2);
    const int row0 = blockIdx.y * 64;
    const int col0 = blockIdx.x * 64;   // within [0,128)

    __shared__ float As[32][65];  // [k][m]
    __shared__ float Bs[32][65];  // [k][c]

    const int tid = threadIdx.x;
    const int tx = tid & 15;      // 0..15 -> 4 cols each
    const int ty = tid >> 4;      // 0..15 -> 4 rows each

    float acc[4][4] = {};

    for (int kk = 0; kk < 128; kk += 32) {
        #pragma unroll
        for (int i = 0; i < 2; ++i) {
            int idx = tid + i * 256;
            int r  = idx >> 3;          // 0..63
            int k4 = idx & 7;           // 0..7
            int grow = row0 + r;
            float4 v = make_float4(0.f, 0.f, 0.f, 0.f);
            if (grow < n)
                v = *(const float4*)(A + (size_t)grow * 128 + kk + k4 * 4);
            As[k4 * 4 + 0][r] = v.x;
            As[k4 * 4 + 1][r] = v.y;
            As[k4 * 4 + 2][r] = v.z;
            As[k4 * 4 + 3][r] = v.w;
        }
        #pragma unroll
        for (int i = 0; i < 2; ++i) {
            int idx = tid + i * 256;
            int kr = idx >> 4;          // 0..31
            int c4 = idx & 15;          // 0..15
            float4 v = *(const float4*)(W + (size_t)(kk + kr) * 128 + col0 + c4 * 4);
            Bs[kr][c4 * 4 + 0] = v.x;
            Bs[kr][c4 * 4 + 1] = v.y;
            Bs[kr][c4 * 4 + 2] = v.z;
            Bs[kr][c4 * 4 + 3] = v.w;
        }
        __syncthreads();
        #pragma unroll
        for (int k = 0; k < 32; ++k) {
            float4 a4 = *(const float4*)&As[k][ty * 4];
            float4 b4 = *(const float4*)&Bs[k][tx * 4];
            float a[4] = {a4.x, a4.y, a4.z, a4.w};
            float b[4] = {b4.x, b4.y, b4.z, b4.w};
            #pragma unroll
            for (int i = 0; i < 4; ++i)
                #pragma unroll
                for (int j = 0; j < 4; ++j)
                    acc[i][j] += a[i] * b[j];
        }
        __syncthreads();
    }

    const int cbase = z * 128 + col0 + tx * 4;
    #pragma unroll
    for (int i = 0; i < 4; ++i) {
        int r = row0 + ty * 4 + i;
        if (r < n) {
            float4 v = make_float4(acc[i][0], acc[i][1], acc[i][2], acc[i][3]);
            *(float4*)(C + (size_t)r * 384 + cbase) = v;
        }
    }
}

// ---------------------------------------------------------------------------
// Attention scores: a_s[n,h] = sum_c xs[n,h,c]*att_src[h,c]; same for a_d.
// ---------------------------------------------------------------------------
__global__ __launch_bounds__(256) void attn_scores_kernel(
    const float* __restrict__ buf,       // [n,384] xs|xd|skip
    const float* __restrict__ att_src,   // [128]
    const float* __restrict__ att_dst,
    float* __restrict__ a_s, float* __restrict__ a_d, int n)
{
    int idx = blockIdx.x * blockDim.x + threadIdx.x;
    if (idx >= n * 4) return;
    int node = idx >> 2, h = idx & 3;
    const float* xs = buf + (size_t)node * 384 + h * 32;
    const float* xd = xs + 128;
    float s = 0.f, d = 0.f;
    #pragma unroll
    for (int c4 = 0; c4 < 8; ++c4) {
        float4 vs  = *(const float4*)(xs + c4 * 4);
        float4 vd  = *(const float4*)(xd + c4 * 4);
        float4 as4 = *(const float4*)(att_src + h * 32 + c4 * 4);
        float4 ad4 = *(const float4*)(att_dst + h * 32 + c4 * 4);
        s += vs.x * as4.x + vs.y * as4.y + vs.z * as4.z + vs.w * as4.w;
        d += vd.x * ad4.x + vd.y * ad4.y + vd.z * ad4.z + vd.w * ad4.w;
    }
    a_s[idx] = s;
    a_d[idx] = d;
}

// ---------------------------------------------------------------------------
// CSR build: histogram / single-block scan / scatter
// ---------------------------------------------------------------------------
__global__ __launch_bounds__(256) void hist_kernel(
    const int* __restrict__ dst, int* __restrict__ deg, int e)
{
    int i = blockIdx.x * blockDim.x + threadIdx.x;
    if (i < e) atomicAdd(&deg[dst[i]], 1);
}

__global__ __launch_bounds__(1024) void scan_kernel(
    const int* __restrict__ deg, int* __restrict__ offs, int n)
{
    __shared__ int lds[1024];
    __shared__ int carry_s;
    if (threadIdx.x == 0) carry_s = 0;
    __syncthreads();
    for (int base = 0; base < n; base += 1024) {
        int i = base + (int)threadIdx.x;
        int v = (i < n) ? deg[i] : 0;
        lds[threadIdx.x] = v;
        __syncthreads();
        #pragma unroll
        for (int off = 1; off < 1024; off <<= 1) {
            int t = (threadIdx.x >= (unsigned)off) ? lds[threadIdx.x - off] : 0;
            __syncthreads();
            lds[threadIdx.x] += t;
            __syncthreads();
        }
        int incl = lds[threadIdx.x];
        int c = carry_s;
        if (i < n) offs[i] = c + incl - v;
        int total = lds[1023];
        __syncthreads();
        if (threadIdx.x == 0) carry_s = c + total;
        __syncthreads();
    }
    if (threadIdx.x == 0) offs[n] = carry_s;
}

__global__ __launch_bounds__(256) void scatter_kernel(
    const int* __restrict__ src, const int* __restrict__ dst,
    const int* __restrict__ offs, int* __restrict__ cursor,
    int* __restrict__ srcSorted, int e)
{
    int i = blockIdx.x * blockDim.x + threadIdx.x;
    if (i >= e) return;
    int d = dst[i];
    int pos = offs[d] + atomicAdd(&cursor[d], 1);
    srcSorted[pos] = src[i];
}

// ---------------------------------------------------------------------------
// Fused softmax + aggregate over CSR: one wave per dst node.
// gat[node] = (sum_j ee_j * xs[src_j]) / (sum_j ee_j), ee = exp(lrelu(as+ad)).
// Lane covers channels {lane, lane+64} -> heads {lane>>5, 2+(lane>>5)}.
// ---------------------------------------------------------------------------
__global__ __launch_bounds__(256) void aggregate_csr_kernel(
    const int* __restrict__ srcSorted, const int* __restrict__ offs,
    const float* __restrict__ buf,      // xs at cols 0..127, row stride 384
    const float* __restrict__ a_s, const float* __restrict__ a_d,
    float* __restrict__ gat, int n)
{
    int node = (blockIdx.x * blockDim.x + threadIdx.x) >> 6;
    int lane = threadIdx.x & 63;
    if (node >= n) return;
    int beg = offs[node], end = offs[node + 1];
    int h0 = lane >> 5;                       // 0..1
    float ad0 = a_d[(size_t)node * 4 + h0];
    float ad1 = a_d[(size_t)node * 4 + 2 + h0];
    float num0 = 0.f, num1 = 0.f, den0 = 0.f, den1 = 0.f;
    for (int t = beg; t < end; ++t) {
        int s = srcSorted[t];
        float as0 = a_s[(size_t)s * 4 + h0];
        float as1 = a_s[(size_t)s * 4 + 2 + h0];
        float e0 = as0 + ad0; e0 = (e0 > 0.f) ? e0 : LRELU * e0;
        float e1 = as1 + ad1; e1 = (e1 > 0.f) ? e1 : LRELU * e1;
        float ee0 = __expf(e0), ee1 = __expf(e1);
        const float* xs = buf + (size_t)s * 384;
        num0 += ee0 * xs[lane];
        num1 += ee1 * xs[lane + 64];
        den0 += ee0;
        den1 += ee1;
    }
    gat[(size_t)node * 128 + lane]      = num0 / (den0 + 1e-16f);
    gat[(size_t)node * 128 + 64 + lane] = num1 / (den1 + 1e-16f);
}

// ---------------------------------------------------------------------------
// h = relu(LN(gat + b1 + skip + bl1) * gamma + beta). One wave per node.
// ---------------------------------------------------------------------------
__global__ __launch_bounds__(256) void ln_relu_kernel(
    const float* __restrict__ gat, const float* __restrict__ buf,
    const float* __restrict__ b1, const float* __restrict__ bl1,
    const float* __restrict__ gamma, const float* __restrict__ beta,
    float* __restrict__ h, int n)
{
    int wave = (blockIdx.x * blockDim.x + threadIdx.x) >> 6;
    int lane = threadIdx.x & 63;
    if (wave >= n) return;
    const float* g0 = gat + (size_t)wave * 128;
    const float* sk = buf + (size_t)wave * 384 + 256;
    float v0 = g0[lane]      + sk[lane]      + b1[lane]      + bl1[lane];
    float v1 = g0[lane + 64] + sk[lane + 64] + b1[lane + 64] + bl1[lane + 64];
    float sum = v0 + v1, sq = v0 * v0 + v1 * v1;
    #pragma unroll
    for (int off = 32; off; off >>= 1) {
        sum += __shfl_xor(sum, off);
        sq  += __shfl_xor(sq, off);
    }
    float mu = sum * (1.f / 128.f);
    float var = sq * (1.f / 128.f) - mu * mu;
    float rs = rsqrtf(var + LN_EPS);
    float o0 = (v0 - mu) * rs * gamma[lane]      + beta[lane];
    float o1 = (v1 - mu) * rs * gamma[lane + 64] + beta[lane + 64];
    h[(size_t)wave * 128 + lane]      = fmaxf(o0, 0.f);
    h[(size_t)wave * 128 + 64 + lane] = fmaxf(o1, 0.f);
}

// ---------------------------------------------------------------------------
// out = gat2 + b2 + skip2 + bl2
// ---------------------------------------------------------------------------
__global__ __launch_bounds__(256) void final_add_kernel(
    const float* __restrict__ gat, const float* __restrict__ buf,
    const float* __restrict__ b2, const float* __restrict__ bl2,
    float* __restrict__ out, int n)
{
    int idx = blockIdx.x * blockDim.x + threadIdx.x;
    if (idx >= n * 128) return;
    int node = idx >> 7, c = idx & 127;
    out[idx] = gat[idx] + buf[(size_t)node * 384 + 256 + c] + b2[c] + bl2[c];
}

extern "C" void kernel_launch(void* const* d_in, const int* in_sizes, int n_in,
                              void* d_out, int out_size, void* d_ws, size_t ws_size,
                              hipStream_t stream) {
    const float* x       = (const float*)d_in[0];
    const int*   ei      = (const int*)d_in[1];
    const int*   src     = ei;
    const int*   dst     = ei + E_EDGES;
    const float* W1_src  = (const float*)d_in[2];
    const float* W1_dst  = (const float*)d_in[3];
    const float* att1_s  = (const float*)d_in[4];
    const float* att1_d  = (const float*)d_in[5];
    const float* b1      = (const float*)d_in[6];
    const float* Wl1     = (const float*)d_in[7];
    const float* bl1     = (const float*)d_in[8];
    const float* gamma   = (const float*)d_in[9];
    const float* beta    = (const float*)d_in[10];
    const float* W2_src  = (const float*)d_in[11];
    const float* W2_dst  = (const float*)d_in[12];
    const float* att2_s  = (const float*)d_in[13];
    const float* att2_d  = (const float*)d_in[14];
    const float* b2      = (const float*)d_in[15];
    const float* Wl2     = (const float*)d_in[16];
    const float* bl2     = (const float*)d_in[17];
    float* out = (float*)d_out;

    float* buf   = (float*)d_ws;                          // N*384 f
    float* a_s   = buf   + (size_t)N_NODES * 384;         // N*4 f
    float* a_d   = a_s   + (size_t)N_NODES * 4;           // N*4 f
    float* gat   = a_d   + (size_t)N_NODES * 4;           // N*128 f
    float* hbuf  = gat   + (size_t)N_NODES * 128;         // N*128 f
    int* deg       = (int*)(hbuf + (size_t)N_NODES * 128);  // N
    int* offs      = deg + N_NODES;                          // N+1
    int* cursor    = offs + N_NODES + 1;                     // N
    int* srcSorted = cursor + N_NODES;                       // E

    dim3 ggrid(2, (N_NODES + 63) / 64, 3);
    int attn_grid  = (N_NODES * 4 + 255) / 256;
    int hist_grid  = (E_EDGES + 255) / 256;
    int agg_grid   = (N_NODES + 3) / 4;
    int ln_grid    = (N_NODES + 3) / 4;
    int final_grid = (N_NODES * 128 + 255) / 256;

    // -------- CSR build (graph constant across both layers) --------
    hipMemsetAsync(deg,    0, (size_t)N_NODES * sizeof(int), stream);
    hipMemsetAsync(cursor, 0, (size_t)N_NODES * sizeof(int), stream);
    hist_kernel<<<hist_grid, 256, 0, stream>>>(dst, deg, E_EDGES);
    scan_kernel<<<1, 1024, 0, stream>>>(deg, offs, N_NODES);
    scatter_kernel<<<hist_grid, 256, 0, stream>>>(src, dst, offs, cursor, srcSorted, E_EDGES);

    // -------- layer 1 --------
    gemm3_kernel<<<ggrid, 256, 0, stream>>>(x, W1_src, W1_dst, Wl1, buf, N_NODES);
    attn_scores_kernel<<<attn_grid, 256, 0, stream>>>(buf, att1_s, att1_d, a_s, a_d, N_NODES);
    aggregate_csr_kernel<<<agg_grid, 256, 0, stream>>>(srcSorted, offs, buf, a_s, a_d, gat, N_NODES);
    ln_relu_kernel<<<ln_grid, 256, 0, stream>>>(gat, buf, b1, bl1, gamma, beta, hbuf, N_NODES);

    // -------- layer 2 --------
    gemm3_kernel<<<ggrid, 256, 0, stream>>>(hbuf, W2_src, W2_dst, Wl2, buf, N_NODES);
    attn_scores_kernel<<<attn_grid, 256, 0, stream>>>(buf, att2_s, att2_d, a_s, a_d, N_NODES);
    aggregate_csr_kernel<<<agg_grid, 256, 0, stream>>>(srcSorted, offs, buf, a_s, a_d, gat, N_NODES);
    final_add_kernel<<<final_grid, 256, 0, stream>>>(gat, buf, b2, bl2, out, N_NODES);
}

// Round 3
// 453.722 us; speedup vs baseline: 3.0043x; 1.5826x over previous
//
#include <hip/hip_runtime.h>

#define N_NODES 50000
#define E_EDGES 800000
#define LRELU 0.2f
#define LN_EPS 1e-5f

typedef short bf16x8 __attribute__((ext_vector_type(8)));
typedef float f32x4 __attribute__((ext_vector_type(4)));

__device__ __forceinline__ ushort f2bf(float f) {
    uint u = __float_as_uint(f);
    u += 0x7FFF + ((u >> 16) & 1);          // RNE
    return (ushort)(u >> 16);
}
__device__ __forceinline__ float bf2f(ushort u) {
    return __uint_as_float(((uint)u) << 16);
}

// ---------------------------------------------------------------------------
// cast x (fp32) -> bf16
// ---------------------------------------------------------------------------
__global__ __launch_bounds__(256) void cast_bf16_kernel(
    const float* __restrict__ x, ushort* __restrict__ xbf, int total4)
{
    int i = blockIdx.x * blockDim.x + threadIdx.x;
    if (i >= total4) return;
    float4 v = *(const float4*)(x + (size_t)i * 4);
    ushort4 o;
    o.x = f2bf(v.x); o.y = f2bf(v.y); o.z = f2bf(v.z); o.w = f2bf(v.w);
    *(ushort4*)(xbf + (size_t)i * 4) = o;
}

// ---------------------------------------------------------------------------
// Pre-transpose + cast weights: Wt[z][n][k] = bf16(Wz[k][n]); z0=W_src, z1=Wl
// ---------------------------------------------------------------------------
__global__ __launch_bounds__(256) void prep_wt_kernel(
    const float* __restrict__ Wsrc, const float* __restrict__ Wl,
    ushort* __restrict__ Wt)
{
    int idx = blockIdx.x * blockDim.x + threadIdx.x;   // 32768
    if (idx >= 32768) return;
    int z = idx >> 14, rem = idx & 16383;
    int nn = rem >> 7, k = rem & 127;
    const float* W = z ? Wl : Wsrc;
    Wt[idx] = f2bf(W[k * 128 + nn]);
}

// ---------------------------------------------------------------------------
// Fold attention vectors into weights: Wsa[f][h] = sum_c Wsrc[f][h*32+c]*att_s[h*32+c]
// ---------------------------------------------------------------------------
__global__ __launch_bounds__(1024) void fold_att_kernel(
    const float* __restrict__ Wsrc, const float* __restrict__ att_s,
    const float* __restrict__ Wdst, const float* __restrict__ att_d,
    float* __restrict__ Wsa, float* __restrict__ Wda)
{
    int t = threadIdx.x;
    const float* W  = (t < 512) ? Wsrc : Wdst;
    const float* av = (t < 512) ? att_s : att_d;
    float* o        = (t < 512) ? Wsa : Wda;
    int tt = t & 511;
    int f = tt >> 2, h = tt & 3;
    float s = 0.f;
    #pragma unroll
    for (int c = 0; c < 32; ++c)
        s += W[f * 128 + h * 32 + c] * av[h * 32 + c];
    o[f * 4 + h] = s;
}

// ---------------------------------------------------------------------------
// MFMA GEMM: Cbf[n, z*128+col] = bf16( Abf[n,:] @ Wt[z][col][:] ), C stride 256.
// grid (2, ceil(n/64)); block 256 = 4 waves (2m x 2n), wave = 32x64 tile.
// ---------------------------------------------------------------------------
__global__ __launch_bounds__(256) void gemm_mfma_kernel(
    const ushort* __restrict__ Abf,   // [n][128] bf16
    const ushort* __restrict__ Wt,    // [2][128(n)][128(k)] bf16
    ushort* __restrict__ Cbf,         // [n][256] bf16
    int n)
{
    __shared__ ushort Asb[64][136];
    __shared__ ushort Wsb[128][136];
    const int z = blockIdx.x;
    const int row0 = blockIdx.y * 64;
    const int tid = threadIdx.x;

    #pragma unroll
    for (int i = 0; i < 4; ++i) {          // A: 64 rows x 128 k
        int c = tid + i * 256;
        int r = c >> 4, o = c & 15;
        int grow = row0 + r;
        uint4 v = make_uint4(0, 0, 0, 0);
        if (grow < n) v = *(const uint4*)(Abf + (size_t)grow * 128 + o * 8);
        *(uint4*)&Asb[r][o * 8] = v;
    }
    #pragma unroll
    for (int i = 0; i < 8; ++i) {          // W: 128 n-rows x 128 k
        int c = tid + i * 256;
        int r = c >> 4, o = c & 15;
        uint4 v = *(const uint4*)(Wt + (size_t)z * 16384 + r * 128 + o * 8);
        *(uint4*)&Wsb[r][o * 8] = v;
    }
    __syncthreads();

    const int w = tid >> 6, lane = tid & 63;
    const int wm = w >> 1, wn = w & 1;
    const int l15 = lane & 15, lg = lane >> 4;

    f32x4 acc[2][4];
    #pragma unroll
    for (int m = 0; m < 2; ++m)
        #pragma unroll
        for (int j = 0; j < 4; ++j)
            acc[m][j] = (f32x4){0.f, 0.f, 0.f, 0.f};

    #pragma unroll
    for (int ks = 0; ks < 4; ++ks) {
        const int k0 = ks * 32 + 4 * lg;
        bf16x8 af[2], bfr[4];
        #pragma unroll
        for (int m = 0; m < 2; ++m) {
            const ushort* p = &Asb[wm * 32 + m * 16 + l15][k0];
            ushort4 lo = *(const ushort4*)p;
            ushort4 hi = *(const ushort4*)(p + 16);
            bf16x8 a;
            a[0] = (short)lo.x; a[1] = (short)lo.y; a[2] = (short)lo.z; a[3] = (short)lo.w;
            a[4] = (short)hi.x; a[5] = (short)hi.y; a[6] = (short)hi.z; a[7] = (short)hi.w;
            af[m] = a;
        }
        #pragma unroll
        for (int j = 0; j < 4; ++j) {
            const ushort* p = &Wsb[wn * 64 + j * 16 + l15][k0];
            ushort4 lo = *(const ushort4*)p;
            ushort4 hi = *(const ushort4*)(p + 16);
            bf16x8 b;
            b[0] = (short)lo.x; b[1] = (short)lo.y; b[2] = (short)lo.z; b[3] = (short)lo.w;
            b[4] = (short)hi.x; b[5] = (short)hi.y; b[6] = (short)hi.z; b[7] = (short)hi.w;
            bfr[j] = b;
        }
        #pragma unroll
        for (int m = 0; m < 2; ++m)
            #pragma unroll
            for (int j = 0; j < 4; ++j)
                acc[m][j] = __builtin_amdgcn_mfma_f32_16x16x32_bf16(
                    af[m], bfr[j], acc[m][j], 0, 0, 0);
    }

    #pragma unroll
    for (int m = 0; m < 2; ++m)
        #pragma unroll
        for (int j = 0; j < 4; ++j)
            #pragma unroll
            for (int r = 0; r < 4; ++r) {
                int grow = row0 + wm * 32 + m * 16 + lg * 4 + r;
                if (grow < n)
                    Cbf[(size_t)grow * 256 + z * 128 + wn * 64 + j * 16 + l15] =
                        f2bf(acc[m][j][r]);
            }
}

// ---------------------------------------------------------------------------
// a_s[n,h] = xbf[n,:] @ Wsa[:,h]; a_d likewise. One thread per node.
// ---------------------------------------------------------------------------
__global__ __launch_bounds__(256) void a_sd_kernel(
    const ushort* __restrict__ xbf, const float* __restrict__ Wsa,
    const float* __restrict__ Wda,
    float* __restrict__ a_s, float* __restrict__ a_d, int n)
{
    __shared__ float Ws[512], Wd[512];
    int t = threadIdx.x;
    Ws[t] = Wsa[t]; Ws[t + 256] = Wsa[t + 256];
    Wd[t] = Wda[t]; Wd[t + 256] = Wda[t + 256];
    __syncthreads();
    int node = blockIdx.x * blockDim.x + t;
    if (node >= n) return;
    const ushort* xr = xbf + (size_t)node * 128;
    float as[4] = {0.f, 0.f, 0.f, 0.f}, ad[4] = {0.f, 0.f, 0.f, 0.f};
    #pragma unroll
    for (int i = 0; i < 16; ++i) {
        uint4 raw = *(const uint4*)(xr + i * 8);
        uint uu[4] = {raw.x, raw.y, raw.z, raw.w};
        #pragma unroll
        for (int q = 0; q < 4; ++q) {
            float f0 = __uint_as_float(uu[q] << 16);
            float f1 = __uint_as_float(uu[q] & 0xFFFF0000u);
            int fidx = i * 8 + q * 2;
            #pragma unroll
            for (int h = 0; h < 4; ++h) {
                as[h] += f0 * Ws[fidx * 4 + h] + f1 * Ws[(fidx + 1) * 4 + h];
                ad[h] += f0 * Wd[fidx * 4 + h] + f1 * Wd[(fidx + 1) * 4 + h];
            }
        }
    }
    *(float4*)(a_s + (size_t)node * 4) = make_float4(as[0], as[1], as[2], as[3]);
    *(float4*)(a_d + (size_t)node * 4) = make_float4(ad[0], ad[1], ad[2], ad[3]);
}

// ---------------------------------------------------------------------------
// CSR build: histogram / hierarchical scan / scatter
// ---------------------------------------------------------------------------
__global__ __launch_bounds__(256) void hist_kernel(
    const int* __restrict__ dst, int* __restrict__ deg, int e)
{
    int i = blockIdx.x * blockDim.x + threadIdx.x;
    if (i < e) atomicAdd(&deg[dst[i]], 1);
}

__global__ __launch_bounds__(1024) void scan1_kernel(
    const int* __restrict__ deg, int* __restrict__ offs,
    int* __restrict__ totals, int n)
{
    __shared__ int lds[1024];
    int t = threadIdx.x;
    int i = blockIdx.x * 1024 + t;
    int v = (i < n) ? deg[i] : 0;
    lds[t] = v;
    __syncthreads();
    #pragma unroll
    for (int off = 1; off < 1024; off <<= 1) {
        int tv = (t >= off) ? lds[t - off] : 0;
        __syncthreads();
        lds[t] += tv;
        __syncthreads();
    }
    if (i < n) offs[i] = lds[t] - v;
    if (t == 1023) totals[blockIdx.x] = lds[1023];
}

__global__ __launch_bounds__(64) void scan2_kernel(
    const int* __restrict__ totals, int* __restrict__ blockOff, int nb)
{
    int lane = threadIdx.x;
    int v = (lane < nb) ? totals[lane] : 0;
    int orig = v;
    #pragma unroll
    for (int off = 1; off < 64; off <<= 1) {
        int tv = __shfl_up(v, off);
        if (lane >= off) v += tv;
    }
    if (lane < nb) blockOff[lane] = v - orig;
}

__global__ __launch_bounds__(256) void scan3_kernel(
    int* __restrict__ offs, const int* __restrict__ blockOff, int n, int e)
{
    int i = blockIdx.x * blockDim.x + threadIdx.x;
    if (i < n) offs[i] += blockOff[i >> 10];
    if (i == 0) offs[n] = e;
}

__global__ __launch_bounds__(256) void scatter_kernel(
    const int* __restrict__ src, const int* __restrict__ dst,
    const int* __restrict__ offs, int* __restrict__ cursor,
    int* __restrict__ srcSorted, int e)
{
    int i = blockIdx.x * blockDim.x + threadIdx.x;
    if (i >= e) return;
    int d = dst[i];
    int pos = offs[d] + atomicAdd(&cursor[d], 1);
    srcSorted[pos] = src[i];
}

// ---------------------------------------------------------------------------
// Fused softmax + aggregate over CSR: one wave per dst node.
// ---------------------------------------------------------------------------
__global__ __launch_bounds__(256) void aggregate_csr_kernel(
    const int* __restrict__ srcSorted, const int* __restrict__ offs,
    const ushort* __restrict__ bufbf,   // xs at cols 0..127, row stride 256
    const float* __restrict__ a_s, const float* __restrict__ a_d,
    float* __restrict__ gat, int n)
{
    int node = (blockIdx.x * blockDim.x + threadIdx.x) >> 6;
    int lane = threadIdx.x & 63;
    if (node >= n) return;
    int beg = offs[node], end = offs[node + 1];
    int h0 = lane >> 5;
    float ad0 = a_d[(size_t)node * 4 + h0];
    float ad1 = a_d[(size_t)node * 4 + 2 + h0];
    float num0 = 0.f, num1 = 0.f, den0 = 0.f, den1 = 0.f;
    for (int t = beg; t < end; ++t) {
        int s = srcSorted[t];
        float as0 = a_s[(size_t)s * 4 + h0];
        float as1 = a_s[(size_t)s * 4 + 2 + h0];
        float e0 = as0 + ad0; e0 = (e0 > 0.f) ? e0 : LRELU * e0;
        float e1 = as1 + ad1; e1 = (e1 > 0.f) ? e1 : LRELU * e1;
        float ee0 = __expf(e0), ee1 = __expf(e1);
        const ushort* xs = bufbf + (size_t)s * 256;
        num0 += ee0 * bf2f(xs[lane]);
        num1 += ee1 * bf2f(xs[lane + 64]);
        den0 += ee0;
        den1 += ee1;
    }
    gat[(size_t)node * 128 + lane]      = num0 / (den0 + 1e-16f);
    gat[(size_t)node * 128 + 64 + lane] = num1 / (den1 + 1e-16f);
}

// ---------------------------------------------------------------------------
// h = bf16(relu(LN(gat + skip + b1 + bl1) * gamma + beta)). One wave per node.
// ---------------------------------------------------------------------------
__global__ __launch_bounds__(256) void ln_relu_kernel(
    const float* __restrict__ gat, const ushort* __restrict__ bufbf,
    const float* __restrict__ b1, const float* __restrict__ bl1,
    const float* __restrict__ gamma, const float* __restrict__ beta,
    ushort* __restrict__ hbf, int n)
{
    int wave = (blockIdx.x * blockDim.x + threadIdx.x) >> 6;
    int lane = threadIdx.x & 63;
    if (wave >= n) return;
    const float* g0 = gat + (size_t)wave * 128;
    const ushort* sk = bufbf + (size_t)wave * 256 + 128;
    float v0 = g0[lane]      + bf2f(sk[lane])      + b1[lane]      + bl1[lane];
    float v1 = g0[lane + 64] + bf2f(sk[lane + 64]) + b1[lane + 64] + bl1[lane + 64];
    float sum = v0 + v1, sq = v0 * v0 + v1 * v1;
    #pragma unroll
    for (int off = 32; off; off >>= 1) {
        sum += __shfl_xor(sum, off);
        sq  += __shfl_xor(sq, off);
    }
    float mu = sum * (1.f / 128.f);
    float var = sq * (1.f / 128.f) - mu * mu;
    float rs = rsqrtf(var + LN_EPS);
    float o0 = (v0 - mu) * rs * gamma[lane]      + beta[lane];
    float o1 = (v1 - mu) * rs * gamma[lane + 64] + beta[lane + 64];
    hbf[(size_t)wave * 128 + lane]      = f2bf(fmaxf(o0, 0.f));
    hbf[(size_t)wave * 128 + 64 + lane] = f2bf(fmaxf(o1, 0.f));
}

// ---------------------------------------------------------------------------
// out (fp32) = gat2 + skip2 + b2 + bl2
// ---------------------------------------------------------------------------
__global__ __launch_bounds__(256) void final_add_kernel(
    const float* __restrict__ gat, const ushort* __restrict__ bufbf,
    const float* __restrict__ b2, const float* __restrict__ bl2,
    float* __restrict__ out, int n)
{
    int idx = blockIdx.x * blockDim.x + threadIdx.x;
    if (idx >= n * 128) return;
    int node = idx >> 7, c = idx & 127;
    out[idx] = gat[idx] + bf2f(bufbf[(size_t)node * 256 + 128 + c]) + b2[c] + bl2[c];
}

extern "C" void kernel_launch(void* const* d_in, const int* in_sizes, int n_in,
                              void* d_out, int out_size, void* d_ws, size_t ws_size,
                              hipStream_t stream) {
    const float* x       = (const float*)d_in[0];
    const int*   ei      = (const int*)d_in[1];
    const int*   src     = ei;
    const int*   dst     = ei + E_EDGES;
    const float* W1_src  = (const float*)d_in[2];
    const float* W1_dst  = (const float*)d_in[3];
    const float* att1_s  = (const float*)d_in[4];
    const float* att1_d  = (const float*)d_in[5];
    const float* b1      = (const float*)d_in[6];
    const float* Wl1     = (const float*)d_in[7];
    const float* bl1     = (const float*)d_in[8];
    const float* gamma   = (const float*)d_in[9];
    const float* beta    = (const float*)d_in[10];
    const float* W2_src  = (const float*)d_in[11];
    const float* W2_dst  = (const float*)d_in[12];
    const float* att2_s  = (const float*)d_in[13];
    const float* att2_d  = (const float*)d_in[14];
    const float* b2      = (const float*)d_in[15];
    const float* Wl2     = (const float*)d_in[16];
    const float* bl2     = (const float*)d_in[17];
    float* out = (float*)d_out;

    // workspace layout
    char* p = (char*)d_ws;
    float* gat   = (float*)p;            p += (size_t)N_NODES * 128 * 4;
    float* a_s   = (float*)p;            p += (size_t)N_NODES * 4 * 4;
    float* a_d   = (float*)p;            p += (size_t)N_NODES * 4 * 4;
    float* Wsa   = (float*)p;            p += 512 * 4;
    float* Wda   = (float*)p;            p += 512 * 4;
    ushort* xbf  = (ushort*)p;           p += (size_t)N_NODES * 128 * 2;
    ushort* hbf  = (ushort*)p;           p += (size_t)N_NODES * 128 * 2;
    ushort* bufbf = (ushort*)p;          p += (size_t)N_NODES * 256 * 2;
    ushort* Wtbf = (ushort*)p;           p += 32768 * 2;
    int* deg       = (int*)p;            p += (size_t)N_NODES * 4;
    int* cursor    = (int*)p;            p += (size_t)N_NODES * 4;
    int* offs      = (int*)p;            p += (size_t)(N_NODES + 1) * 4;
    int* totals    = (int*)p;            p += 64 * 4;
    int* blockOff  = (int*)p;            p += 64 * 4;
    int* srcSorted = (int*)p;            p += (size_t)E_EDGES * 4;

    const int NB = (N_NODES + 1023) / 1024;   // 49
    dim3 ggrid(2, (N_NODES + 63) / 64);
    int cast_grid  = (N_NODES * 128 / 4 + 255) / 256;
    int node_grid  = (N_NODES + 255) / 256;
    int hist_grid  = (E_EDGES + 255) / 256;
    int wave_grid  = (N_NODES + 3) / 4;
    int final_grid = (N_NODES * 128 + 255) / 256;

    // -------- CSR build --------
    hipMemsetAsync(deg,    0, (size_t)N_NODES * sizeof(int), stream);
    hipMemsetAsync(cursor, 0, (size_t)N_NODES * sizeof(int), stream);
    hist_kernel<<<hist_grid, 256, 0, stream>>>(dst, deg, E_EDGES);
    scan1_kernel<<<NB, 1024, 0, stream>>>(deg, offs, totals, N_NODES);
    scan2_kernel<<<1, 64, 0, stream>>>(totals, blockOff, NB);
    scan3_kernel<<<node_grid, 256, 0, stream>>>(offs, blockOff, N_NODES, E_EDGES);
    scatter_kernel<<<hist_grid, 256, 0, stream>>>(src, dst, offs, cursor, srcSorted, E_EDGES);

    cast_bf16_kernel<<<cast_grid, 256, 0, stream>>>(x, xbf, N_NODES * 128 / 4);

    // -------- layer 1 --------
    prep_wt_kernel<<<128, 256, 0, stream>>>(W1_src, Wl1, Wtbf);
    fold_att_kernel<<<1, 1024, 0, stream>>>(W1_src, att1_s, W1_dst, att1_d, Wsa, Wda);
    gemm_mfma_kernel<<<ggrid, 256, 0, stream>>>(xbf, Wtbf, bufbf, N_NODES);
    a_sd_kernel<<<node_grid, 256, 0, stream>>>(xbf, Wsa, Wda, a_s, a_d, N_NODES);
    aggregate_csr_kernel<<<wave_grid, 256, 0, stream>>>(srcSorted, offs, bufbf, a_s, a_d, gat, N_NODES);
    ln_relu_kernel<<<wave_grid, 256, 0, stream>>>(gat, bufbf, b1, bl1, gamma, beta, hbf, N_NODES);

    // -------- layer 2 --------
    prep_wt_kernel<<<128, 256, 0, stream>>>(W2_src, Wl2, Wtbf);
    fold_att_kernel<<<1, 1024, 0, stream>>>(W2_src, att2_s, W2_dst, att2_d, Wsa, Wda);
    gemm_mfma_kernel<<<ggrid, 256, 0, stream>>>(hbf, Wtbf, bufbf, N_NODES);
    a_sd_kernel<<<node_grid, 256, 0, stream>>>(hbf, Wsa, Wda, a_s, a_d, N_NODES);
    aggregate_csr_kernel<<<wave_grid, 256, 0, stream>>>(srcSorted, offs, bufbf, a_s, a_d, gat, N_NODES);
    final_add_kernel<<<final_grid, 256, 0, stream>>>(gat, bufbf, b2, bl2, out, N_NODES);
}

// Round 4
// 381.626 us; speedup vs baseline: 3.5719x; 1.1889x over previous
//
#include <hip/hip_runtime.h>

#define N_NODES 50000
#define E_EDGES 800000
#define LRELU 0.2f
#define LN_EPS 1e-5f

typedef short bf16x8 __attribute__((ext_vector_type(8)));
typedef float f32x4 __attribute__((ext_vector_type(4)));

__device__ __forceinline__ ushort f2bf(float f) {
    uint u = __float_as_uint(f);
    u += 0x7FFF + ((u >> 16) & 1);          // RNE
    return (ushort)(u >> 16);
}
__device__ __forceinline__ float bf2f(ushort u) {
    return __uint_as_float(((uint)u) << 16);
}
__device__ __forceinline__ float bflo(uint u) {   // low ushort -> float
    return __uint_as_float(u << 16);
}
__device__ __forceinline__ float bfhi(uint u) {   // high ushort -> float
    return __uint_as_float(u & 0xFFFF0000u);
}

// ---------------------------------------------------------------------------
// cast x (fp32) -> bf16
// ---------------------------------------------------------------------------
__global__ __launch_bounds__(256) void cast_bf16_kernel(
    const float* __restrict__ x, ushort* __restrict__ xbf, int total4)
{
    int i = blockIdx.x * blockDim.x + threadIdx.x;
    if (i >= total4) return;
    float4 v = *(const float4*)(x + (size_t)i * 4);
    ushort4 o;
    o.x = f2bf(v.x); o.y = f2bf(v.y); o.z = f2bf(v.z); o.w = f2bf(v.w);
    *(ushort4*)(xbf + (size_t)i * 4) = o;
}

// ---------------------------------------------------------------------------
// Pre-transpose + cast weights: Wt[z][n][k] = bf16(Wz[k][n]); z0=W_src, z1=Wl
// ---------------------------------------------------------------------------
__global__ __launch_bounds__(256) void prep_wt_kernel(
    const float* __restrict__ Wsrc, const float* __restrict__ Wl,
    ushort* __restrict__ Wt)
{
    int idx = blockIdx.x * blockDim.x + threadIdx.x;   // 32768
    if (idx >= 32768) return;
    int z = idx >> 14, rem = idx & 16383;
    int nn = rem >> 7, k = rem & 127;
    const float* W = z ? Wl : Wsrc;
    Wt[idx] = f2bf(W[k * 128 + nn]);
}

// ---------------------------------------------------------------------------
// Fold attention vectors into weights: Wsa[f][h] = sum_c Wsrc[f][h*32+c]*att_s[h*32+c]
// ---------------------------------------------------------------------------
__global__ __launch_bounds__(1024) void fold_att_kernel(
    const float* __restrict__ Wsrc, const float* __restrict__ att_s,
    const float* __restrict__ Wdst, const float* __restrict__ att_d,
    float* __restrict__ Wsa, float* __restrict__ Wda)
{
    int t = threadIdx.x;
    const float* W  = (t < 512) ? Wsrc : Wdst;
    const float* av = (t < 512) ? att_s : att_d;
    float* o        = (t < 512) ? Wsa : Wda;
    int tt = t & 511;
    int f = tt >> 2, h = tt & 3;
    float s = 0.f;
    #pragma unroll
    for (int c = 0; c < 32; ++c)
        s += W[f * 128 + h * 32 + c] * av[h * 32 + c];
    o[f * 4 + h] = s;
}

// ---------------------------------------------------------------------------
// MFMA GEMM: Cbf[n, z*128+col] = bf16( Abf[n,:] @ Wt[z][col][:] ), C stride 256.
// grid (2, ceil(n/64)); block 256 = 4 waves (2m x 2n), wave = 32x64 tile.
// ---------------------------------------------------------------------------
__global__ __launch_bounds__(256) void gemm_mfma_kernel(
    const ushort* __restrict__ Abf,   // [n][128] bf16
    const ushort* __restrict__ Wt,    // [2][128(n)][128(k)] bf16
    ushort* __restrict__ Cbf,         // [n][256] bf16
    int n)
{
    __shared__ ushort Asb[64][136];
    __shared__ ushort Wsb[128][136];
    const int z = blockIdx.x;
    const int row0 = blockIdx.y * 64;
    const int tid = threadIdx.x;

    #pragma unroll
    for (int i = 0; i < 4; ++i) {          // A: 64 rows x 128 k
        int c = tid + i * 256;
        int r = c >> 4, o = c & 15;
        int grow = row0 + r;
        uint4 v = make_uint4(0, 0, 0, 0);
        if (grow < n) v = *(const uint4*)(Abf + (size_t)grow * 128 + o * 8);
        *(uint4*)&Asb[r][o * 8] = v;
    }
    #pragma unroll
    for (int i = 0; i < 8; ++i) {          // W: 128 n-rows x 128 k
        int c = tid + i * 256;
        int r = c >> 4, o = c & 15;
        uint4 v = *(const uint4*)(Wt + (size_t)z * 16384 + r * 128 + o * 8);
        *(uint4*)&Wsb[r][o * 8] = v;
    }
    __syncthreads();

    const int w = tid >> 6, lane = tid & 63;
    const int wm = w >> 1, wn = w & 1;
    const int l15 = lane & 15, lg = lane >> 4;

    f32x4 acc[2][4];
    #pragma unroll
    for (int m = 0; m < 2; ++m)
        #pragma unroll
        for (int j = 0; j < 4; ++j)
            acc[m][j] = (f32x4){0.f, 0.f, 0.f, 0.f};

    #pragma unroll
    for (int ks = 0; ks < 4; ++ks) {
        const int k0 = ks * 32 + 4 * lg;
        bf16x8 af[2], bfr[4];
        #pragma unroll
        for (int m = 0; m < 2; ++m) {
            const ushort* p = &Asb[wm * 32 + m * 16 + l15][k0];
            ushort4 lo = *(const ushort4*)p;
            ushort4 hi = *(const ushort4*)(p + 16);
            bf16x8 a;
            a[0] = (short)lo.x; a[1] = (short)lo.y; a[2] = (short)lo.z; a[3] = (short)lo.w;
            a[4] = (short)hi.x; a[5] = (short)hi.y; a[6] = (short)hi.z; a[7] = (short)hi.w;
            af[m] = a;
        }
        #pragma unroll
        for (int j = 0; j < 4; ++j) {
            const ushort* p = &Wsb[wn * 64 + j * 16 + l15][k0];
            ushort4 lo = *(const ushort4*)p;
            ushort4 hi = *(const ushort4*)(p + 16);
            bf16x8 b;
            b[0] = (short)lo.x; b[1] = (short)lo.y; b[2] = (short)lo.z; b[3] = (short)lo.w;
            b[4] = (short)hi.x; b[5] = (short)hi.y; b[6] = (short)hi.z; b[7] = (short)hi.w;
            bfr[j] = b;
        }
        #pragma unroll
        for (int m = 0; m < 2; ++m)
            #pragma unroll
            for (int j = 0; j < 4; ++j)
                acc[m][j] = __builtin_amdgcn_mfma_f32_16x16x32_bf16(
                    af[m], bfr[j], acc[m][j], 0, 0, 0);
    }

    #pragma unroll
    for (int m = 0; m < 2; ++m)
        #pragma unroll
        for (int j = 0; j < 4; ++j)
            #pragma unroll
            for (int r = 0; r < 4; ++r) {
                int grow = row0 + wm * 32 + m * 16 + lg * 4 + r;
                if (grow < n)
                    Cbf[(size_t)grow * 256 + z * 128 + wn * 64 + j * 16 + l15] =
                        f2bf(acc[m][j][r]);
            }
}

// ---------------------------------------------------------------------------
// a_s[n,h] = xbf[n,:] @ Wsa[:,h]; a_d likewise. One thread per node.
// ---------------------------------------------------------------------------
__global__ __launch_bounds__(256) void a_sd_kernel(
    const ushort* __restrict__ xbf, const float* __restrict__ Wsa,
    const float* __restrict__ Wda,
    float* __restrict__ a_s, float* __restrict__ a_d, int n)
{
    __shared__ float Ws[512], Wd[512];
    int t = threadIdx.x;
    Ws[t] = Wsa[t]; Ws[t + 256] = Wsa[t + 256];
    Wd[t] = Wda[t]; Wd[t + 256] = Wda[t + 256];
    __syncthreads();
    int node = blockIdx.x * blockDim.x + t;
    if (node >= n) return;
    const ushort* xr = xbf + (size_t)node * 128;
    float as[4] = {0.f, 0.f, 0.f, 0.f}, ad[4] = {0.f, 0.f, 0.f, 0.f};
    #pragma unroll
    for (int i = 0; i < 16; ++i) {
        uint4 raw = *(const uint4*)(xr + i * 8);
        uint uu[4] = {raw.x, raw.y, raw.z, raw.w};
        #pragma unroll
        for (int q = 0; q < 4; ++q) {
            float f0 = bflo(uu[q]);
            float f1 = bfhi(uu[q]);
            int fidx = i * 8 + q * 2;
            #pragma unroll
            for (int h = 0; h < 4; ++h) {
                as[h] += f0 * Ws[fidx * 4 + h] + f1 * Ws[(fidx + 1) * 4 + h];
                ad[h] += f0 * Wd[fidx * 4 + h] + f1 * Wd[(fidx + 1) * 4 + h];
            }
        }
    }
    *(float4*)(a_s + (size_t)node * 4) = make_float4(as[0], as[1], as[2], as[3]);
    *(float4*)(a_d + (size_t)node * 4) = make_float4(ad[0], ad[1], ad[2], ad[3]);
}

// ---------------------------------------------------------------------------
// CSR build: histogram / hierarchical scan / scatter
// ---------------------------------------------------------------------------
__global__ __launch_bounds__(256) void hist_kernel(
    const int* __restrict__ dst, int* __restrict__ deg, int e)
{
    int i = blockIdx.x * blockDim.x + threadIdx.x;
    if (i < e) atomicAdd(&deg[dst[i]], 1);
}

__global__ __launch_bounds__(1024) void scan1_kernel(
    const int* __restrict__ deg, int* __restrict__ offs,
    int* __restrict__ totals, int n)
{
    __shared__ int lds[1024];
    int t = threadIdx.x;
    int i = blockIdx.x * 1024 + t;
    int v = (i < n) ? deg[i] : 0;
    lds[t] = v;
    __syncthreads();
    #pragma unroll
    for (int off = 1; off < 1024; off <<= 1) {
        int tv = (t >= off) ? lds[t - off] : 0;
        __syncthreads();
        lds[t] += tv;
        __syncthreads();
    }
    if (i < n) offs[i] = lds[t] - v;
    if (t == 1023) totals[blockIdx.x] = lds[1023];
}

__global__ __launch_bounds__(64) void scan2_kernel(
    const int* __restrict__ totals, int* __restrict__ blockOff, int nb)
{
    int lane = threadIdx.x;
    int v = (lane < nb) ? totals[lane] : 0;
    int orig = v;
    #pragma unroll
    for (int off = 1; off < 64; off <<= 1) {
        int tv = __shfl_up(v, off);
        if (lane >= off) v += tv;
    }
    if (lane < nb) blockOff[lane] = v - orig;
}

__global__ __launch_bounds__(256) void scan3_kernel(
    int* __restrict__ offs, int* __restrict__ cursor,
    const int* __restrict__ blockOff, int n, int e)
{
    int i = blockIdx.x * blockDim.x + threadIdx.x;
    if (i < n) {
        int v = offs[i] + blockOff[i >> 10];
        offs[i] = v;
        cursor[i] = v;
    }
    if (i == 0) offs[n] = e;
}

__global__ __launch_bounds__(256) void scatter_kernel(
    const int* __restrict__ src, const int* __restrict__ dst,
    int* __restrict__ cursor, int* __restrict__ srcSorted, int e)
{
    int i = blockIdx.x * blockDim.x + threadIdx.x;
    if (i >= e) return;
    int d = dst[i];
    int pos = atomicAdd(&cursor[d], 1);
    srcSorted[pos] = src[i];
}

// ---------------------------------------------------------------------------
// Fused softmax + aggregate + epilogue. One wave per dst node.
// Lane handles channels {2*lane, 2*lane+1}, head = lane>>4.
// MODE 0: +skip+b+bl -> LayerNorm -> ReLU -> hbf (bf16)
// MODE 1: +skip+b+bl -> out (fp32)
// ---------------------------------------------------------------------------
template <int MODE>
__global__ __launch_bounds__(256) void aggregate_fused_kernel(
    const int* __restrict__ srcSorted, const int* __restrict__ offs,
    const ushort* __restrict__ bufbf,   // [n][256] xs|skip (bf16)
    const float* __restrict__ a_s, const float* __restrict__ a_d,
    const float* __restrict__ bias_a,   // b [128]
    const float* __restrict__ bias_l,   // bl [128]
    const float* __restrict__ gamma, const float* __restrict__ beta,
    ushort* __restrict__ hbf, float* __restrict__ out, int n)
{
    int node = (blockIdx.x * blockDim.x + threadIdx.x) >> 6;
    int lane = threadIdx.x & 63;
    if (node >= n) return;
    int beg = offs[node], end = offs[node + 1];
    int h = lane >> 4;
    float ad = a_d[(size_t)node * 4 + h];
    float num0 = 0.f, num1 = 0.f, den = 0.f;

    int t = beg;
    for (; t + 1 < end; t += 2) {
        int s0 = srcSorted[t];
        int s1 = srcSorted[t + 1];
        float as0 = a_s[(size_t)s0 * 4 + h];
        float as1 = a_s[(size_t)s1 * 4 + h];
        uint x0 = *(const uint*)(bufbf + (size_t)s0 * 256 + 2 * lane);
        uint x1 = *(const uint*)(bufbf + (size_t)s1 * 256 + 2 * lane);
        float e0 = as0 + ad; e0 = (e0 > 0.f) ? e0 : LRELU * e0;
        float e1 = as1 + ad; e1 = (e1 > 0.f) ? e1 : LRELU * e1;
        float ee0 = __expf(e0), ee1 = __expf(e1);
        num0 += ee0 * bflo(x0) + ee1 * bflo(x1);
        num1 += ee0 * bfhi(x0) + ee1 * bfhi(x1);
        den  += ee0 + ee1;
    }
    if (t < end) {
        int s0 = srcSorted[t];
        float as0 = a_s[(size_t)s0 * 4 + h];
        uint x0 = *(const uint*)(bufbf + (size_t)s0 * 256 + 2 * lane);
        float e0 = as0 + ad; e0 = (e0 > 0.f) ? e0 : LRELU * e0;
        float ee0 = __expf(e0);
        num0 += ee0 * bflo(x0);
        num1 += ee0 * bfhi(x0);
        den  += ee0;
    }

    float inv = 1.f / (den + 1e-16f);
    uint sk = *(const uint*)(bufbf + (size_t)node * 256 + 128 + 2 * lane);
    float2 ba = *(const float2*)(bias_a + 2 * lane);
    float2 bl = *(const float2*)(bias_l + 2 * lane);
    float v0 = num0 * inv + bflo(sk) + ba.x + bl.x;
    float v1 = num1 * inv + bfhi(sk) + ba.y + bl.y;

    if (MODE == 0) {
        float sum = v0 + v1, sq = v0 * v0 + v1 * v1;
        #pragma unroll
        for (int off = 32; off; off >>= 1) {
            sum += __shfl_xor(sum, off);
            sq  += __shfl_xor(sq, off);
        }
        float mu = sum * (1.f / 128.f);
        float var = sq * (1.f / 128.f) - mu * mu;
        float rs = rsqrtf(var + LN_EPS);
        float2 gm = *(const float2*)(gamma + 2 * lane);
        float2 bt = *(const float2*)(beta + 2 * lane);
        float o0 = fmaxf((v0 - mu) * rs * gm.x + bt.x, 0.f);
        float o1 = fmaxf((v1 - mu) * rs * gm.y + bt.y, 0.f);
        uint packed = (uint)f2bf(o0) | ((uint)f2bf(o1) << 16);
        *(uint*)(hbf + (size_t)node * 128 + 2 * lane) = packed;
    } else {
        *(float2*)(out + (size_t)node * 128 + 2 * lane) = make_float2(v0, v1);
    }
}

extern "C" void kernel_launch(void* const* d_in, const int* in_sizes, int n_in,
                              void* d_out, int out_size, void* d_ws, size_t ws_size,
                              hipStream_t stream) {
    const float* x       = (const float*)d_in[0];
    const int*   ei      = (const int*)d_in[1];
    const int*   src     = ei;
    const int*   dst     = ei + E_EDGES;
    const float* W1_src  = (const float*)d_in[2];
    const float* W1_dst  = (const float*)d_in[3];
    const float* att1_s  = (const float*)d_in[4];
    const float* att1_d  = (const float*)d_in[5];
    const float* b1      = (const float*)d_in[6];
    const float* Wl1     = (const float*)d_in[7];
    const float* bl1     = (const float*)d_in[8];
    const float* gamma   = (const float*)d_in[9];
    const float* beta    = (const float*)d_in[10];
    const float* W2_src  = (const float*)d_in[11];
    const float* W2_dst  = (const float*)d_in[12];
    const float* att2_s  = (const float*)d_in[13];
    const float* att2_d  = (const float*)d_in[14];
    const float* b2      = (const float*)d_in[15];
    const float* Wl2     = (const float*)d_in[16];
    const float* bl2     = (const float*)d_in[17];
    float* out = (float*)d_out;

    // workspace layout
    char* p = (char*)d_ws;
    float* a_s   = (float*)p;            p += (size_t)N_NODES * 4 * 4;
    float* a_d   = (float*)p;            p += (size_t)N_NODES * 4 * 4;
    float* Wsa   = (float*)p;            p += 512 * 4;
    float* Wda   = (float*)p;            p += 512 * 4;
    ushort* xbf  = (ushort*)p;           p += (size_t)N_NODES * 128 * 2;
    ushort* hbf  = (ushort*)p;           p += (size_t)N_NODES * 128 * 2;
    ushort* bufbf = (ushort*)p;          p += (size_t)N_NODES * 256 * 2;
    ushort* Wtbf = (ushort*)p;           p += 32768 * 2;
    int* deg       = (int*)p;            p += (size_t)N_NODES * 4;
    int* cursor    = (int*)p;            p += (size_t)N_NODES * 4;
    int* offs      = (int*)p;            p += (size_t)(N_NODES + 1) * 4;
    int* totals    = (int*)p;            p += 64 * 4;
    int* blockOff  = (int*)p;            p += 64 * 4;
    int* srcSorted = (int*)p;            p += (size_t)E_EDGES * 4;

    const int NB = (N_NODES + 1023) / 1024;   // 49
    dim3 ggrid(2, (N_NODES + 63) / 64);
    int cast_grid  = (N_NODES * 128 / 4 + 255) / 256;
    int node_grid  = (N_NODES + 255) / 256;
    int hist_grid  = (E_EDGES + 255) / 256;
    int wave_grid  = (N_NODES + 3) / 4;

    // -------- CSR build --------
    hipMemsetAsync(deg, 0, (size_t)N_NODES * sizeof(int), stream);
    hist_kernel<<<hist_grid, 256, 0, stream>>>(dst, deg, E_EDGES);
    scan1_kernel<<<NB, 1024, 0, stream>>>(deg, offs, totals, N_NODES);
    scan2_kernel<<<1, 64, 0, stream>>>(totals, blockOff, NB);
    scan3_kernel<<<node_grid, 256, 0, stream>>>(offs, cursor, blockOff, N_NODES, E_EDGES);
    scatter_kernel<<<hist_grid, 256, 0, stream>>>(src, dst, cursor, srcSorted, E_EDGES);

    cast_bf16_kernel<<<cast_grid, 256, 0, stream>>>(x, xbf, N_NODES * 128 / 4);

    // -------- layer 1 --------
    prep_wt_kernel<<<128, 256, 0, stream>>>(W1_src, Wl1, Wtbf);
    fold_att_kernel<<<1, 1024, 0, stream>>>(W1_src, att1_s, W1_dst, att1_d, Wsa, Wda);
    gemm_mfma_kernel<<<ggrid, 256, 0, stream>>>(xbf, Wtbf, bufbf, N_NODES);
    a_sd_kernel<<<node_grid, 256, 0, stream>>>(xbf, Wsa, Wda, a_s, a_d, N_NODES);
    aggregate_fused_kernel<0><<<wave_grid, 256, 0, stream>>>(
        srcSorted, offs, bufbf, a_s, a_d, b1, bl1, gamma, beta, hbf, nullptr, N_NODES);

    // -------- layer 2 --------
    prep_wt_kernel<<<128, 256, 0, stream>>>(W2_src, Wl2, Wtbf);
    fold_att_kernel<<<1, 1024, 0, stream>>>(W2_src, att2_s, W2_dst, att2_d, Wsa, Wda);
    gemm_mfma_kernel<<<ggrid, 256, 0, stream>>>(hbf, Wtbf, bufbf, N_NODES);
    a_sd_kernel<<<node_grid, 256, 0, stream>>>(hbf, Wsa, Wda, a_s, a_d, N_NODES);
    aggregate_fused_kernel<1><<<wave_grid, 256, 0, stream>>>(
        srcSorted, offs, bufbf, a_s, a_d, b2, bl2, nullptr, nullptr, nullptr, out, N_NODES);
}

// Round 5
// 369.696 us; speedup vs baseline: 3.6871x; 1.0323x over previous
//
#include <hip/hip_runtime.h>

#define N_NODES 50000
#define E_EDGES 800000
#define LRELU 0.2f
#define LN_EPS 1e-5f

typedef short bf16x8 __attribute__((ext_vector_type(8)));
typedef float f32x4 __attribute__((ext_vector_type(4)));

__device__ __forceinline__ ushort f2bf(float f) {
    uint u = __float_as_uint(f);
    u += 0x7FFF + ((u >> 16) & 1);          // RNE
    return (ushort)(u >> 16);
}
__device__ __forceinline__ float bflo(uint u) {   // low ushort -> float
    return __uint_as_float(u << 16);
}
__device__ __forceinline__ float bfhi(uint u) {   // high ushort -> float
    return __uint_as_float(u & 0xFFFF0000u);
}

// ---------------------------------------------------------------------------
// cast x (fp32) -> bf16, and zero deg[] (saves a memset dispatch)
// ---------------------------------------------------------------------------
__global__ __launch_bounds__(256) void cast_bf16_kernel(
    const float* __restrict__ x, ushort* __restrict__ xbf,
    int* __restrict__ deg, int total4)
{
    int i = blockIdx.x * blockDim.x + threadIdx.x;
    if (i < N_NODES) deg[i] = 0;
    if (i >= total4) return;
    float4 v = *(const float4*)(x + (size_t)i * 4);
    ushort4 o;
    o.x = f2bf(v.x); o.y = f2bf(v.y); o.z = f2bf(v.z); o.w = f2bf(v.w);
    *(ushort4*)(xbf + (size_t)i * 4) = o;
}

// ---------------------------------------------------------------------------
// Per-layer weight prep, one dispatch:
//   blocks 0..127 : Wt[z][n][k] = bf16(Wz[k][n])   (z0=W_src, z1=Wl)
//   block  128    : Wsa[f][h] = sum_c Wsrc[f][h*32+c]*att_s[h*32+c]; same Wda
// ---------------------------------------------------------------------------
__global__ __launch_bounds__(256) void prep_layer_kernel(
    const float* __restrict__ Wsrc, const float* __restrict__ Wl,
    const float* __restrict__ Wdst,
    const float* __restrict__ att_s, const float* __restrict__ att_d,
    ushort* __restrict__ Wt, float* __restrict__ Wsa, float* __restrict__ Wda)
{
    int t = threadIdx.x;
    if (blockIdx.x < 128) {
        int idx = blockIdx.x * 256 + t;       // 32768
        int z = idx >> 14, rem = idx & 16383;
        int nn = rem >> 7, k = rem & 127;
        const float* W = z ? Wl : Wsrc;
        Wt[idx] = f2bf(W[k * 128 + nn]);
    } else {
        #pragma unroll
        for (int r = 0; r < 4; ++r) {
            int idx = r * 256 + t;            // 1024
            const float* W  = (idx < 512) ? Wsrc : Wdst;
            const float* av = (idx < 512) ? att_s : att_d;
            float* o        = (idx < 512) ? Wsa : Wda;
            int tt = idx & 511;
            int f = tt >> 2, h = tt & 3;
            float s = 0.f;
            #pragma unroll
            for (int c = 0; c < 32; ++c)
                s += W[f * 128 + h * 32 + c] * av[h * 32 + c];
            o[f * 4 + h] = s;
        }
    }
}

// ---------------------------------------------------------------------------
// MFMA GEMM: Cbf[n, z*128+col] = bf16( Abf[n,:] @ Wt[z][col][:] ), C stride 256.
// grid (2, ceil(n/64)); block 256 = 4 waves (2m x 2n), wave = 32x64 tile.
// ---------------------------------------------------------------------------
__global__ __launch_bounds__(256) void gemm_mfma_kernel(
    const ushort* __restrict__ Abf,   // [n][128] bf16
    const ushort* __restrict__ Wt,    // [2][128(n)][128(k)] bf16
    ushort* __restrict__ Cbf,         // [n][256] bf16
    int n)
{
    __shared__ ushort Asb[64][136];
    __shared__ ushort Wsb[128][136];
    const int z = blockIdx.x;
    const int row0 = blockIdx.y * 64;
    const int tid = threadIdx.x;

    #pragma unroll
    for (int i = 0; i < 4; ++i) {          // A: 64 rows x 128 k
        int c = tid + i * 256;
        int r = c >> 4, o = c & 15;
        int grow = row0 + r;
        uint4 v = make_uint4(0, 0, 0, 0);
        if (grow < n) v = *(const uint4*)(Abf + (size_t)grow * 128 + o * 8);
        *(uint4*)&Asb[r][o * 8] = v;
    }
    #pragma unroll
    for (int i = 0; i < 8; ++i) {          // W: 128 n-rows x 128 k
        int c = tid + i * 256;
        int r = c >> 4, o = c & 15;
        uint4 v = *(const uint4*)(Wt + (size_t)z * 16384 + r * 128 + o * 8);
        *(uint4*)&Wsb[r][o * 8] = v;
    }
    __syncthreads();

    const int w = tid >> 6, lane = tid & 63;
    const int wm = w >> 1, wn = w & 1;
    const int l15 = lane & 15, lg = lane >> 4;

    f32x4 acc[2][4];
    #pragma unroll
    for (int m = 0; m < 2; ++m)
        #pragma unroll
        for (int j = 0; j < 4; ++j)
            acc[m][j] = (f32x4){0.f, 0.f, 0.f, 0.f};

    #pragma unroll
    for (int ks = 0; ks < 4; ++ks) {
        const int k0 = ks * 32 + 4 * lg;
        bf16x8 af[2], bfr[4];
        #pragma unroll
        for (int m = 0; m < 2; ++m) {
            const ushort* p = &Asb[wm * 32 + m * 16 + l15][k0];
            ushort4 lo = *(const ushort4*)p;
            ushort4 hi = *(const ushort4*)(p + 16);
            bf16x8 a;
            a[0] = (short)lo.x; a[1] = (short)lo.y; a[2] = (short)lo.z; a[3] = (short)lo.w;
            a[4] = (short)hi.x; a[5] = (short)hi.y; a[6] = (short)hi.z; a[7] = (short)hi.w;
            af[m] = a;
        }
        #pragma unroll
        for (int j = 0; j < 4; ++j) {
            const ushort* p = &Wsb[wn * 64 + j * 16 + l15][k0];
            ushort4 lo = *(const ushort4*)p;
            ushort4 hi = *(const ushort4*)(p + 16);
            bf16x8 b;
            b[0] = (short)lo.x; b[1] = (short)lo.y; b[2] = (short)lo.z; b[3] = (short)lo.w;
            b[4] = (short)hi.x; b[5] = (short)hi.y; b[6] = (short)hi.z; b[7] = (short)hi.w;
            bfr[j] = b;
        }
        #pragma unroll
        for (int m = 0; m < 2; ++m)
            #pragma unroll
            for (int j = 0; j < 4; ++j)
                acc[m][j] = __builtin_amdgcn_mfma_f32_16x16x32_bf16(
                    af[m], bfr[j], acc[m][j], 0, 0, 0);
    }

    #pragma unroll
    for (int m = 0; m < 2; ++m)
        #pragma unroll
        for (int j = 0; j < 4; ++j)
            #pragma unroll
            for (int r = 0; r < 4; ++r) {
                int grow = row0 + wm * 32 + m * 16 + lg * 4 + r;
                if (grow < n)
                    Cbf[(size_t)grow * 256 + z * 128 + wn * 64 + j * 16 + l15] =
                        f2bf(acc[m][j][r]);
            }
}

// ---------------------------------------------------------------------------
// a_s[n,h] = xbf[n,:] @ Wsa[:,h]; a_d likewise. One thread per node.
// ---------------------------------------------------------------------------
__global__ __launch_bounds__(256) void a_sd_kernel(
    const ushort* __restrict__ xbf, const float* __restrict__ Wsa,
    const float* __restrict__ Wda,
    float* __restrict__ a_s, float* __restrict__ a_d, int n)
{
    __shared__ float Ws[512], Wd[512];
    int t = threadIdx.x;
    Ws[t] = Wsa[t]; Ws[t + 256] = Wsa[t + 256];
    Wd[t] = Wda[t]; Wd[t + 256] = Wda[t + 256];
    __syncthreads();
    int node = blockIdx.x * blockDim.x + t;
    if (node >= n) return;
    const ushort* xr = xbf + (size_t)node * 128;
    float as[4] = {0.f, 0.f, 0.f, 0.f}, ad[4] = {0.f, 0.f, 0.f, 0.f};
    #pragma unroll
    for (int i = 0; i < 16; ++i) {
        uint4 raw = *(const uint4*)(xr + i * 8);
        uint uu[4] = {raw.x, raw.y, raw.z, raw.w};
        #pragma unroll
        for (int q = 0; q < 4; ++q) {
            float f0 = bflo(uu[q]);
            float f1 = bfhi(uu[q]);
            int fidx = i * 8 + q * 2;
            #pragma unroll
            for (int h = 0; h < 4; ++h) {
                as[h] += f0 * Ws[fidx * 4 + h] + f1 * Ws[(fidx + 1) * 4 + h];
                ad[h] += f0 * Wd[fidx * 4 + h] + f1 * Wd[(fidx + 1) * 4 + h];
            }
        }
    }
    *(float4*)(a_s + (size_t)node * 4) = make_float4(as[0], as[1], as[2], as[3]);
    *(float4*)(a_d + (size_t)node * 4) = make_float4(ad[0], ad[1], ad[2], ad[3]);
}

// ---------------------------------------------------------------------------
// CSR build: histogram / hierarchical scan / scatter
// ---------------------------------------------------------------------------
__global__ __launch_bounds__(256) void hist_kernel(
    const int* __restrict__ dst, int* __restrict__ deg, int e)
{
    int i = blockIdx.x * blockDim.x + threadIdx.x;
    if (i < e) atomicAdd(&deg[dst[i]], 1);
}

__global__ __launch_bounds__(1024) void scan1_kernel(
    const int* __restrict__ deg, int* __restrict__ offs,
    int* __restrict__ totals, int n)
{
    __shared__ int lds[1024];
    int t = threadIdx.x;
    int i = blockIdx.x * 1024 + t;
    int v = (i < n) ? deg[i] : 0;
    lds[t] = v;
    __syncthreads();
    #pragma unroll
    for (int off = 1; off < 1024; off <<= 1) {
        int tv = (t >= off) ? lds[t - off] : 0;
        __syncthreads();
        lds[t] += tv;
        __syncthreads();
    }
    if (i < n) offs[i] = lds[t] - v;
    if (t == 1023) totals[blockIdx.x] = lds[1023];
}

__global__ __launch_bounds__(64) void scan2_kernel(
    const int* __restrict__ totals, int* __restrict__ blockOff, int nb)
{
    int lane = threadIdx.x;
    int v = (lane < nb) ? totals[lane] : 0;
    int orig = v;
    #pragma unroll
    for (int off = 1; off < 64; off <<= 1) {
        int tv = __shfl_up(v, off);
        if (lane >= off) v += tv;
    }
    if (lane < nb) blockOff[lane] = v - orig;
}

__global__ __launch_bounds__(256) void scan3_kernel(
    int* __restrict__ offs, int* __restrict__ cursor,
    const int* __restrict__ blockOff, int n, int e)
{
    int i = blockIdx.x * blockDim.x + threadIdx.x;
    if (i < n) {
        int v = offs[i] + blockOff[i >> 10];
        offs[i] = v;
        cursor[i] = v;
    }
    if (i == 0) offs[n] = e;
}

__global__ __launch_bounds__(256) void scatter_kernel(
    const int* __restrict__ src, const int* __restrict__ dst,
    int* __restrict__ cursor, int* __restrict__ srcSorted, int e)
{
    int i = blockIdx.x * blockDim.x + threadIdx.x;
    if (i >= e) return;
    int d = dst[i];
    int pos = atomicAdd(&cursor[d], 1);
    srcSorted[pos] = src[i];
}

// ---------------------------------------------------------------------------
// Fused softmax + aggregate + epilogue. One wave per dst node.
// Lane handles channels {2*lane, 2*lane+1}, head h = lane>>4.
// Batch-8 exp dedup: lanes 0-31 compute ee for (edge j=lane&7, head lane>>3),
// distributed via __shfl; removes the 16x-redundant expf from the hot loop.
// MODE 0: +skip+b+bl -> LayerNorm -> ReLU -> hbf (bf16)
// MODE 1: +skip+b+bl -> out (fp32)
// ---------------------------------------------------------------------------
template <int MODE>
__global__ __launch_bounds__(256) void aggregate_fused_kernel(
    const int* __restrict__ srcSorted, const int* __restrict__ offs,
    const ushort* __restrict__ bufbf,   // [n][256] xs|skip (bf16)
    const float* __restrict__ a_s, const float* __restrict__ a_d,
    const float* __restrict__ bias_a,   // b [128]
    const float* __restrict__ bias_l,   // bl [128]
    const float* __restrict__ gamma, const float* __restrict__ beta,
    ushort* __restrict__ hbf, float* __restrict__ out, int n)
{
    int node = (blockIdx.x * blockDim.x + threadIdx.x) >> 6;
    int lane = threadIdx.x & 63;
    if (node >= n) return;
    int beg = offs[node], end = offs[node + 1];
    int h = lane >> 4;
    float ad = a_d[(size_t)node * 4 + h];
    // compute-phase head for lanes 0-31 (head = lane>>3 & 3); get its a_d via shfl
    int hh = (lane >> 3) & 3;
    float adh = __shfl(ad, hh << 4);
    int j8 = lane & 7;
    int h8 = (lane >> 4) << 3;              // base lane of my head's compute slots

    float num0 = 0.f, num1 = 0.f, den = 0.f;
    int t = beg;
    int nb = (end - beg) >> 3;

    for (int b = 0; b < nb; ++b, t += 8) {
        int s = 0; float ee = 0.f;
        if (lane < 32) {
            s = srcSorted[t + j8];
            float as = a_s[(size_t)s * 4 + hh];
            float e = as + adh;
            e = (e > 0.f) ? e : LRELU * e;
            ee = __expf(e);
        }
        #pragma unroll
        for (int q = 0; q < 8; ++q) {
            float eeq = __shfl(ee, h8 + q);
            int   sq  = __shfl(s, q);
            uint xq = *(const uint*)(bufbf + (size_t)sq * 256 + 2 * lane);
            num0 += eeq * bflo(xq);
            num1 += eeq * bfhi(xq);
            den  += eeq;
        }
    }
    for (; t < end; ++t) {
        int s0 = srcSorted[t];
        float as0 = a_s[(size_t)s0 * 4 + h];
        uint x0 = *(const uint*)(bufbf + (size_t)s0 * 256 + 2 * lane);
        float e0 = as0 + ad;
        e0 = (e0 > 0.f) ? e0 : LRELU * e0;
        float ee0 = __expf(e0);
        num0 += ee0 * bflo(x0);
        num1 += ee0 * bfhi(x0);
        den  += ee0;
    }

    float inv = 1.f / (den + 1e-16f);
    uint sk = *(const uint*)(bufbf + (size_t)node * 256 + 128 + 2 * lane);
    float2 ba = *(const float2*)(bias_a + 2 * lane);
    float2 bl = *(const float2*)(bias_l + 2 * lane);
    float v0 = num0 * inv + bflo(sk) + ba.x + bl.x;
    float v1 = num1 * inv + bfhi(sk) + ba.y + bl.y;

    if (MODE == 0) {
        float sum = v0 + v1, sq = v0 * v0 + v1 * v1;
        #pragma unroll
        for (int off = 32; off; off >>= 1) {
            sum += __shfl_xor(sum, off);
            sq  += __shfl_xor(sq, off);
        }
        float mu = sum * (1.f / 128.f);
        float var = sq * (1.f / 128.f) - mu * mu;
        float rs = rsqrtf(var + LN_EPS);
        float2 gm = *(const float2*)(gamma + 2 * lane);
        float2 bt = *(const float2*)(beta + 2 * lane);
        float o0 = fmaxf((v0 - mu) * rs * gm.x + bt.x, 0.f);
        float o1 = fmaxf((v1 - mu) * rs * gm.y + bt.y, 0.f);
        uint packed = (uint)f2bf(o0) | ((uint)f2bf(o1) << 16);
        *(uint*)(hbf + (size_t)node * 128 + 2 * lane) = packed;
    } else {
        *(float2*)(out + (size_t)node * 128 + 2 * lane) = make_float2(v0, v1);
    }
}

extern "C" void kernel_launch(void* const* d_in, const int* in_sizes, int n_in,
                              void* d_out, int out_size, void* d_ws, size_t ws_size,
                              hipStream_t stream) {
    const float* x       = (const float*)d_in[0];
    const int*   ei      = (const int*)d_in[1];
    const int*   src     = ei;
    const int*   dst     = ei + E_EDGES;
    const float* W1_src  = (const float*)d_in[2];
    const float* W1_dst  = (const float*)d_in[3];
    const float* att1_s  = (const float*)d_in[4];
    const float* att1_d  = (const float*)d_in[5];
    const float* b1      = (const float*)d_in[6];
    const float* Wl1     = (const float*)d_in[7];
    const float* bl1     = (const float*)d_in[8];
    const float* gamma   = (const float*)d_in[9];
    const float* beta    = (const float*)d_in[10];
    const float* W2_src  = (const float*)d_in[11];
    const float* W2_dst  = (const float*)d_in[12];
    const float* att2_s  = (const float*)d_in[13];
    const float* att2_d  = (const float*)d_in[14];
    const float* b2      = (const float*)d_in[15];
    const float* Wl2     = (const float*)d_in[16];
    const float* bl2     = (const float*)d_in[17];
    float* out = (float*)d_out;

    // workspace layout
    char* p = (char*)d_ws;
    float* a_s   = (float*)p;            p += (size_t)N_NODES * 4 * 4;
    float* a_d   = (float*)p;            p += (size_t)N_NODES * 4 * 4;
    float* Wsa   = (float*)p;            p += 512 * 4;
    float* Wda   = (float*)p;            p += 512 * 4;
    ushort* xbf  = (ushort*)p;           p += (size_t)N_NODES * 128 * 2;
    ushort* hbf  = (ushort*)p;           p += (size_t)N_NODES * 128 * 2;
    ushort* bufbf = (ushort*)p;          p += (size_t)N_NODES * 256 * 2;
    ushort* Wtbf = (ushort*)p;           p += 32768 * 2;
    int* deg       = (int*)p;            p += (size_t)N_NODES * 4;
    int* cursor    = (int*)p;            p += (size_t)N_NODES * 4;
    int* offs      = (int*)p;            p += (size_t)(N_NODES + 1) * 4;
    int* totals    = (int*)p;            p += 64 * 4;
    int* blockOff  = (int*)p;            p += 64 * 4;
    int* srcSorted = (int*)p;            p += (size_t)E_EDGES * 4;

    const int NB = (N_NODES + 1023) / 1024;   // 49
    dim3 ggrid(2, (N_NODES + 63) / 64);
    int cast_grid  = (N_NODES * 128 / 4 + 255) / 256;
    int node_grid  = (N_NODES + 255) / 256;
    int hist_grid  = (E_EDGES + 255) / 256;
    int wave_grid  = (N_NODES + 3) / 4;

    // -------- CSR build + input cast --------
    cast_bf16_kernel<<<cast_grid, 256, 0, stream>>>(x, xbf, deg, N_NODES * 128 / 4);
    hist_kernel<<<hist_grid, 256, 0, stream>>>(dst, deg, E_EDGES);
    scan1_kernel<<<NB, 1024, 0, stream>>>(deg, offs, totals, N_NODES);
    scan2_kernel<<<1, 64, 0, stream>>>(totals, blockOff, NB);
    scan3_kernel<<<node_grid, 256, 0, stream>>>(offs, cursor, blockOff, N_NODES, E_EDGES);
    scatter_kernel<<<hist_grid, 256, 0, stream>>>(src, dst, cursor, srcSorted, E_EDGES);

    // -------- layer 1 --------
    prep_layer_kernel<<<129, 256, 0, stream>>>(W1_src, Wl1, W1_dst, att1_s, att1_d, Wtbf, Wsa, Wda);
    gemm_mfma_kernel<<<ggrid, 256, 0, stream>>>(xbf, Wtbf, bufbf, N_NODES);
    a_sd_kernel<<<node_grid, 256, 0, stream>>>(xbf, Wsa, Wda, a_s, a_d, N_NODES);
    aggregate_fused_kernel<0><<<wave_grid, 256, 0, stream>>>(
        srcSorted, offs, bufbf, a_s, a_d, b1, bl1, gamma, beta, hbf, nullptr, N_NODES);

    // -------- layer 2 --------
    prep_layer_kernel<<<129, 256, 0, stream>>>(W2_src, Wl2, W2_dst, att2_s, att2_d, Wtbf, Wsa, Wda);
    gemm_mfma_kernel<<<ggrid, 256, 0, stream>>>(hbf, Wtbf, bufbf, N_NODES);
    a_sd_kernel<<<node_grid, 256, 0, stream>>>(hbf, Wsa, Wda, a_s, a_d, N_NODES);
    aggregate_fused_kernel<1><<<wave_grid, 256, 0, stream>>>(
        srcSorted, offs, bufbf, a_s, a_d, b2, bl2, nullptr, nullptr, nullptr, out, N_NODES);
}

// Round 6
// 322.065 us; speedup vs baseline: 4.2325x; 1.1479x over previous
//
#include <hip/hip_runtime.h>

#define N_NODES 50000
#define E_EDGES 800000
#define LRELU 0.2f
#define LN_EPS 1e-5f
#define NBUCK 98              // ceil(50000/512)
#define BSHIFT 9              // 512 nodes per bucket

typedef short bf16x8 __attribute__((ext_vector_type(8)));
typedef float f32x4 __attribute__((ext_vector_type(4)));

__device__ __forceinline__ ushort f2bf(float f) {
    uint u = __float_as_uint(f);
    u += 0x7FFF + ((u >> 16) & 1);          // RNE
    return (ushort)(u >> 16);
}
__device__ __forceinline__ float bflo(uint u) { return __uint_as_float(u << 16); }
__device__ __forceinline__ float bfhi(uint u) { return __uint_as_float(u & 0xFFFF0000u); }

// ---------------------------------------------------------------------------
// CSR stage 1: per-bucket edge counts (LDS hist -> global atomics)
// ---------------------------------------------------------------------------
__global__ __launch_bounds__(256) void bucket_count_kernel(
    const int* __restrict__ dst, int* __restrict__ bucketCnt, int e)
{
    __shared__ int lhist[NBUCK];
    int t = threadIdx.x;
    if (t < NBUCK) lhist[t] = 0;
    __syncthreads();
    int e0 = blockIdx.x * 2048;
    int count = min(2048, e - e0);
    #pragma unroll
    for (int q = 0; q < 8; ++q) {
        int li = t + q * 256;
        if (li < count) atomicAdd(&lhist[dst[e0 + li] >> BSHIFT], 1);
    }
    __syncthreads();
    if (t < NBUCK && lhist[t]) atomicAdd(&bucketCnt[t], lhist[t]);
}

// ---------------------------------------------------------------------------
// CSR stage 2: exclusive scan of 98 bucket counts (1 block, 128 threads)
// ---------------------------------------------------------------------------
__global__ __launch_bounds__(128) void bucket_scan_kernel(
    const int* __restrict__ bucketCnt, int* __restrict__ bucketBase,
    int* __restrict__ bucketCursor)
{
    __shared__ int ls[128];
    int t = threadIdx.x;
    int v = (t < NBUCK) ? bucketCnt[t] : 0;
    ls[t] = v;
    __syncthreads();
    #pragma unroll
    for (int off = 1; off < 128; off <<= 1) {
        int u = (t >= off) ? ls[t - off] : 0;
        __syncthreads();
        ls[t] += u;
        __syncthreads();
    }
    if (t < NBUCK) {
        int ex = ls[t] - v;
        bucketBase[t] = ex;
        bucketCursor[t] = ex;
    }
    if (t == NBUCK - 1) bucketBase[NBUCK] = ls[t];
}

// ---------------------------------------------------------------------------
// CSR stage 3: grouped scatter into bucket regions. Each block stages 2048
// edges in LDS grouped by bucket, reserves contiguous chunks via one global
// atomic per bucket, then writes contiguous runs (full-line writebacks).
// pairs word = src (16b) | dstLow (9b) << 16.
// ---------------------------------------------------------------------------
__global__ __launch_bounds__(256) void bucket_scatter_kernel(
    const int* __restrict__ src, const int* __restrict__ dst,
    int* __restrict__ bucketCursor, uint* __restrict__ pairs, int e)
{
    __shared__ int lhist[128];         // padded for scan
    __shared__ int lscan[NBUCK];
    __shared__ int lcur[NBUCK];
    __shared__ int lbase[NBUCK];
    __shared__ uint stageW[2048];
    __shared__ int  stageA[2048];
    int t = threadIdx.x;
    int e0 = blockIdx.x * 2048;
    int count = min(2048, e - e0);

    if (t < 128) lhist[t] = 0;
    if (t < NBUCK) lcur[t] = 0;
    __syncthreads();

    int  bb[8];
    uint pk[8];
    #pragma unroll
    for (int q = 0; q < 8; ++q) {
        int li = t + q * 256;
        if (li < count) {
            int d = dst[e0 + li];
            int s = src[e0 + li];
            bb[q] = d >> BSHIFT;
            pk[q] = (uint)s | ((uint)(d & 511) << 16);
            atomicAdd(&lhist[bb[q]], 1);
        } else bb[q] = -1;
    }
    __syncthreads();

    int orig = (t < 128) ? lhist[t] : 0;
    #pragma unroll
    for (int off = 1; off < 128; off <<= 1) {
        int u = 0;
        if (t < 128 && t >= off) u = lhist[t - off];
        __syncthreads();
        if (t < 128) lhist[t] += u;
        __syncthreads();
    }
    if (t < NBUCK) {
        lscan[t] = lhist[t] - orig;                       // exclusive
        lbase[t] = orig ? atomicAdd(&bucketCursor[t], orig) : 0;
    }
    __syncthreads();

    #pragma unroll
    for (int q = 0; q < 8; ++q) {
        if (bb[q] >= 0) {
            int slot = lscan[bb[q]] + atomicAdd(&lcur[bb[q]], 1);
            stageW[slot] = pk[q];
            stageA[slot] = lbase[bb[q]] + (slot - lscan[bb[q]]);
        }
    }
    __syncthreads();

    #pragma unroll
    for (int q = 0; q < 8; ++q) {
        int li = t + q * 256;
        if (li < count) pairs[stageA[li]] = stageW[li];
    }
}

// ---------------------------------------------------------------------------
// CSR stage 4: per-bucket sort. One block per bucket (512 threads).
// Builds per-node offsets (writes offs[]) and places edges (srcSorted ushort).
// Bucket region is 32KB -> stays in one XCD's L2 -> full-line writebacks.
// ---------------------------------------------------------------------------
__global__ __launch_bounds__(512) void bucket_sort_kernel(
    const uint* __restrict__ pairs, const int* __restrict__ bucketBase,
    int* __restrict__ offs, ushort* __restrict__ srcSorted, int n, int e)
{
    __shared__ int cnt[512], cur[512], ls[512];
    int b = blockIdx.x, t = threadIdx.x;
    int base = bucketBase[b];
    int m = bucketBase[b + 1] - base;
    cnt[t] = 0; cur[t] = 0;
    __syncthreads();
    for (int i = t; i < m; i += 512)
        atomicAdd(&cnt[pairs[base + i] >> 16], 1);
    __syncthreads();
    int orig = cnt[t];
    ls[t] = orig;
    __syncthreads();
    #pragma unroll
    for (int off = 1; off < 512; off <<= 1) {
        int u = (t >= off) ? ls[t - off] : 0;
        __syncthreads();
        ls[t] += u;
        __syncthreads();
    }
    int excl = ls[t] - orig;
    int node = (b << BSHIFT) + t;
    if (node < n) offs[node] = base + excl;
    if (b == NBUCK - 1 && t == 0) offs[n] = e;
    cnt[t] = excl;                      // reuse as exclusive base
    __syncthreads();
    for (int i = t; i < m; i += 512) {
        uint w = pairs[base + i];
        int dl = w >> 16;
        int pos = cnt[dl] + atomicAdd(&cur[dl], 1);
        srcSorted[base + pos] = (ushort)(w & 0xFFFFu);
    }
}

// ---------------------------------------------------------------------------
// Weight prep for BOTH layers, one dispatch.
// blocks 0..255:  Wt[(L*2+z)][nn][k] = bf16(W[k][nn])  (z0=W_src, z1=Wl)
// blocks 256+L:   Watt[L][c][k]: c<4 -> fold(W_src,att_s), c in 4..7 ->
//                 fold(W_dst,att_d), c>=8 -> 0
// ---------------------------------------------------------------------------
__global__ __launch_bounds__(256) void prep_all_kernel(
    const float* __restrict__ W1s, const float* __restrict__ Wl1,
    const float* __restrict__ W1d, const float* __restrict__ a1s,
    const float* __restrict__ a1d,
    const float* __restrict__ W2s, const float* __restrict__ Wl2,
    const float* __restrict__ W2d, const float* __restrict__ a2s,
    const float* __restrict__ a2d,
    ushort* __restrict__ Wt, ushort* __restrict__ Watt)
{
    int t = threadIdx.x;
    if (blockIdx.x < 256) {
        int idx = blockIdx.x * 256 + t;          // [0,65536)
        int lw = idx >> 14, rem = idx & 16383;
        int nn = rem >> 7, k = rem & 127;
        const float* W = (lw == 0) ? W1s : (lw == 1) ? Wl1 : (lw == 2) ? W2s : Wl2;
        Wt[idx] = f2bf(W[k * 128 + nn]);
    } else {
        int L = blockIdx.x - 256;
        const float* Ws = L ? W2s : W1s;
        const float* Wd = L ? W2d : W1d;
        const float* as = L ? a2s : a1s;
        const float* adv = L ? a2d : a1d;
        #pragma unroll
        for (int q = 0; q < 8; ++q) {
            int e = q * 256 + t;                 // [0,2048)
            int c = e >> 7, f = e & 127;
            float v = 0.f;
            if (c < 8) {
                const float* W  = (c < 4) ? Ws : Wd;
                const float* av = (c < 4) ? as : adv;
                int h = c & 3;
                #pragma unroll
                for (int j = 0; j < 32; ++j)
                    v += W[f * 128 + h * 32 + j] * av[h * 32 + j];
            }
            Watt[L * 2048 + c * 128 + f] = f2bf(v);
        }
    }
}

// ---------------------------------------------------------------------------
// MFMA GEMM + fused attention-score tile.
// grid (2, ceil(n/64)); block 256 = 4 waves (2m x 2n), wave = 32x64 tile.
// z=0 blocks additionally compute a_sd[n][8] = A @ [Wsa|Wda] (16-col tile,
// handled by the wn==0 waves).
// LAYER 0: A = x (fp32, converted during staging). LAYER 1: A = hbf (bf16).
// ---------------------------------------------------------------------------
template <int LAYER>
__global__ __launch_bounds__(256) void gemm_fused_kernel(
    const float* __restrict__ Afp, const ushort* __restrict__ Abf,
    const ushort* __restrict__ Wt, const ushort* __restrict__ Watt,
    ushort* __restrict__ Cbf, float* __restrict__ a_sd, int n)
{
    __shared__ ushort Asb[64][136];
    __shared__ ushort Wsb[128][136];
    __shared__ ushort Attb[16][136];
    const int z = blockIdx.x;
    const int row0 = blockIdx.y * 64;
    const int tid = threadIdx.x;

    if (LAYER == 0) {
        #pragma unroll
        for (int i = 0; i < 8; ++i) {          // 64 rows x 128 k fp32 -> bf16
            int idx = tid + i * 256;
            int r = idx >> 5, c4 = idx & 31;
            int grow = row0 + r;
            float4 v = make_float4(0.f, 0.f, 0.f, 0.f);
            if (grow < n) v = *(const float4*)(Afp + (size_t)grow * 128 + c4 * 4);
            ushort4 o;
            o.x = f2bf(v.x); o.y = f2bf(v.y); o.z = f2bf(v.z); o.w = f2bf(v.w);
            *(ushort4*)&Asb[r][c4 * 4] = o;
        }
    } else {
        #pragma unroll
        for (int i = 0; i < 4; ++i) {          // 64 rows x 128 k bf16
            int c = tid + i * 256;
            int r = c >> 4, o = c & 15;
            int grow = row0 + r;
            uint4 v = make_uint4(0, 0, 0, 0);
            if (grow < n) v = *(const uint4*)(Abf + (size_t)grow * 128 + o * 8);
            *(uint4*)&Asb[r][o * 8] = v;
        }
    }
    {
        const ushort* Wz = Wt + (size_t)(LAYER * 2 + z) * 16384;
        #pragma unroll
        for (int i = 0; i < 8; ++i) {          // 128 n-rows x 128 k
            int c = tid + i * 256;
            int r = c >> 4, o = c & 15;
            uint4 v = *(const uint4*)(Wz + r * 128 + o * 8);
            *(uint4*)&Wsb[r][o * 8] = v;
        }
    }
    if (z == 0) {                              // 16 x 128 att tile
        int r = tid >> 4, o = tid & 15;
        uint4 v = *(const uint4*)(Watt + LAYER * 2048 + r * 128 + o * 8);
        *(uint4*)&Attb[r][o * 8] = v;
    }
    __syncthreads();

    const int w = tid >> 6, lane = tid & 63;
    const int wm = w >> 1, wn = w & 1;
    const int l15 = lane & 15, lg = lane >> 4;
    const bool doAtt = (z == 0) && (wn == 0);

    f32x4 acc[2][4];
    f32x4 accA[2];
    #pragma unroll
    for (int m = 0; m < 2; ++m) {
        accA[m] = (f32x4){0.f, 0.f, 0.f, 0.f};
        #pragma unroll
        for (int j = 0; j < 4; ++j)
            acc[m][j] = (f32x4){0.f, 0.f, 0.f, 0.f};
    }

    #pragma unroll
    for (int ks = 0; ks < 4; ++ks) {
        const int k0 = ks * 32 + 4 * lg;
        bf16x8 af[2], bfr[4];
        #pragma unroll
        for (int m = 0; m < 2; ++m) {
            const ushort* p = &Asb[wm * 32 + m * 16 + l15][k0];
            ushort4 lo = *(const ushort4*)p;
            ushort4 hi = *(const ushort4*)(p + 16);
            bf16x8 a;
            a[0] = (short)lo.x; a[1] = (short)lo.y; a[2] = (short)lo.z; a[3] = (short)lo.w;
            a[4] = (short)hi.x; a[5] = (short)hi.y; a[6] = (short)hi.z; a[7] = (short)hi.w;
            af[m] = a;
        }
        #pragma unroll
        for (int j = 0; j < 4; ++j) {
            const ushort* p = &Wsb[wn * 64 + j * 16 + l15][k0];
            ushort4 lo = *(const ushort4*)p;
            ushort4 hi = *(const ushort4*)(p + 16);
            bf16x8 b;
            b[0] = (short)lo.x; b[1] = (short)lo.y; b[2] = (short)lo.z; b[3] = (short)lo.w;
            b[4] = (short)hi.x; b[5] = (short)hi.y; b[6] = (short)hi.z; b[7] = (short)hi.w;
            bfr[j] = b;
        }
        #pragma unroll
        for (int m = 0; m < 2; ++m)
            #pragma unroll
            for (int j = 0; j < 4; ++j)
                acc[m][j] = __builtin_amdgcn_mfma_f32_16x16x32_bf16(
                    af[m], bfr[j], acc[m][j], 0, 0, 0);
        if (doAtt) {
            const ushort* p = &Attb[l15][k0];
            ushort4 lo = *(const ushort4*)p;
            ushort4 hi = *(const ushort4*)(p + 16);
            bf16x8 b;
            b[0] = (short)lo.x; b[1] = (short)lo.y; b[2] = (short)lo.z; b[3] = (short)lo.w;
            b[4] = (short)hi.x; b[5] = (short)hi.y; b[6] = (short)hi.z; b[7] = (short)hi.w;
            #pragma unroll
            for (int m = 0; m < 2; ++m)
                accA[m] = __builtin_amdgcn_mfma_f32_16x16x32_bf16(
                    af[m], b, accA[m], 0, 0, 0);
        }
    }

    #pragma unroll
    for (int m = 0; m < 2; ++m)
        #pragma unroll
        for (int j = 0; j < 4; ++j)
            #pragma unroll
            for (int r = 0; r < 4; ++r) {
                int grow = row0 + wm * 32 + m * 16 + lg * 4 + r;
                if (grow < n)
                    Cbf[(size_t)grow * 256 + z * 128 + wn * 64 + j * 16 + l15] =
                        f2bf(acc[m][j][r]);
            }
    if (doAtt && l15 < 8) {
        #pragma unroll
        for (int m = 0; m < 2; ++m)
            #pragma unroll
            for (int r = 0; r < 4; ++r) {
                int grow = row0 + wm * 32 + m * 16 + lg * 4 + r;
                if (grow < n) a_sd[(size_t)grow * 8 + l15] = accA[m][r];
            }
    }
}

// ---------------------------------------------------------------------------
// Fused softmax + aggregate + epilogue. One wave per dst node.
// Lane handles channels {2*lane, 2*lane+1}, head h = lane>>4.
// Batch-8 exp dedup via lanes 0-31 + shfl distribution.
// a_sd layout [n][8]: cols 0-3 a_s, 4-7 a_d.
// MODE 0: +skip+b+bl -> LayerNorm -> ReLU -> hbf (bf16)
// MODE 1: +skip+b+bl -> out (fp32)
// ---------------------------------------------------------------------------
template <int MODE>
__global__ __launch_bounds__(256) void aggregate_fused_kernel(
    const ushort* __restrict__ srcSorted, const int* __restrict__ offs,
    const ushort* __restrict__ bufbf,   // [n][256] xs|skip (bf16)
    const float* __restrict__ a_sd,
    const float* __restrict__ bias_a, const float* __restrict__ bias_l,
    const float* __restrict__ gamma, const float* __restrict__ beta,
    ushort* __restrict__ hbf, float* __restrict__ out, int n)
{
    int node = (blockIdx.x * blockDim.x + threadIdx.x) >> 6;
    int lane = threadIdx.x & 63;
    if (node >= n) return;
    int beg = offs[node], end = offs[node + 1];
    int h = lane >> 4;
    float ad = a_sd[(size_t)node * 8 + 4 + h];
    int hh = (lane >> 3) & 3;
    float adh = __shfl(ad, hh << 4);
    int j8 = lane & 7;
    int h8 = (lane >> 4) << 3;

    float num0 = 0.f, num1 = 0.f, den = 0.f;
    int t = beg;
    int nb = (end - beg) >> 3;

    for (int b = 0; b < nb; ++b, t += 8) {
        int s = 0; float ee = 0.f;
        if (lane < 32) {
            s = srcSorted[t + j8];
            float as = a_sd[(size_t)s * 8 + hh];
            float e = as + adh;
            e = (e > 0.f) ? e : LRELU * e;
            ee = __expf(e);
        }
        #pragma unroll
        for (int q = 0; q < 8; ++q) {
            float eeq = __shfl(ee, h8 + q);
            int   sq  = __shfl(s, q);
            uint xq = *(const uint*)(bufbf + (size_t)sq * 256 + 2 * lane);
            num0 += eeq * bflo(xq);
            num1 += eeq * bfhi(xq);
            den  += eeq;
        }
    }
    for (; t < end; ++t) {
        int s0 = srcSorted[t];
        float as0 = a_sd[(size_t)s0 * 8 + h];
        uint x0 = *(const uint*)(bufbf + (size_t)s0 * 256 + 2 * lane);
        float e0 = as0 + ad;
        e0 = (e0 > 0.f) ? e0 : LRELU * e0;
        float ee0 = __expf(e0);
        num0 += ee0 * bflo(x0);
        num1 += ee0 * bfhi(x0);
        den  += ee0;
    }

    float inv = 1.f / (den + 1e-16f);
    uint sk = *(const uint*)(bufbf + (size_t)node * 256 + 128 + 2 * lane);
    float2 ba = *(const float2*)(bias_a + 2 * lane);
    float2 bl = *(const float2*)(bias_l + 2 * lane);
    float v0 = num0 * inv + bflo(sk) + ba.x + bl.x;
    float v1 = num1 * inv + bfhi(sk) + ba.y + bl.y;

    if (MODE == 0) {
        float sum = v0 + v1, sq = v0 * v0 + v1 * v1;
        #pragma unroll
        for (int off = 32; off; off >>= 1) {
            sum += __shfl_xor(sum, off);
            sq  += __shfl_xor(sq, off);
        }
        float mu = sum * (1.f / 128.f);
        float var = sq * (1.f / 128.f) - mu * mu;
        float rs = rsqrtf(var + LN_EPS);
        float2 gm = *(const float2*)(gamma + 2 * lane);
        float2 bt = *(const float2*)(beta + 2 * lane);
        float o0 = fmaxf((v0 - mu) * rs * gm.x + bt.x, 0.f);
        float o1 = fmaxf((v1 - mu) * rs * gm.y + bt.y, 0.f);
        uint packed = (uint)f2bf(o0) | ((uint)f2bf(o1) << 16);
        *(uint*)(hbf + (size_t)node * 128 + 2 * lane) = packed;
    } else {
        *(float2*)(out + (size_t)node * 128 + 2 * lane) = make_float2(v0, v1);
    }
}

extern "C" void kernel_launch(void* const* d_in, const int* in_sizes, int n_in,
                              void* d_out, int out_size, void* d_ws, size_t ws_size,
                              hipStream_t stream) {
    const float* x       = (const float*)d_in[0];
    const int*   ei      = (const int*)d_in[1];
    const int*   src     = ei;
    const int*   dst     = ei + E_EDGES;
    const float* W1_src  = (const float*)d_in[2];
    const float* W1_dst  = (const float*)d_in[3];
    const float* att1_s  = (const float*)d_in[4];
    const float* att1_d  = (const float*)d_in[5];
    const float* b1      = (const float*)d_in[6];
    const float* Wl1     = (const float*)d_in[7];
    const float* bl1     = (const float*)d_in[8];
    const float* gamma   = (const float*)d_in[9];
    const float* beta    = (const float*)d_in[10];
    const float* W2_src  = (const float*)d_in[11];
    const float* W2_dst  = (const float*)d_in[12];
    const float* att2_s  = (const float*)d_in[13];
    const float* att2_d  = (const float*)d_in[14];
    const float* b2      = (const float*)d_in[15];
    const float* Wl2     = (const float*)d_in[16];
    const float* bl2     = (const float*)d_in[17];
    float* out = (float*)d_out;

    // workspace layout (4B-aligned items first, then 2B arrays)
    char* p = (char*)d_ws;
    float* a_sd        = (float*)p;      p += (size_t)N_NODES * 8 * 4;
    int* offs          = (int*)p;        p += (size_t)(N_NODES + 1) * 4;
    int* bucketCnt     = (int*)p;        p += (NBUCK) * 4;
    int* bucketBase    = (int*)p;        p += (NBUCK + 1) * 4;
    int* bucketCursor  = (int*)p;        p += (NBUCK + 1) * 4;   // keep 16B align
    uint* pairs        = (uint*)p;       p += (size_t)E_EDGES * 4;
    ushort* hbf        = (ushort*)p;     p += (size_t)N_NODES * 128 * 2;
    ushort* bufbf      = (ushort*)p;     p += (size_t)N_NODES * 256 * 2;
    ushort* Wt         = (ushort*)p;     p += (size_t)4 * 16384 * 2;
    ushort* Watt       = (ushort*)p;     p += (size_t)2 * 2048 * 2;
    ushort* srcSorted  = (ushort*)p;     p += (size_t)E_EDGES * 2;

    dim3 ggrid(2, (N_NODES + 63) / 64);
    int edge_blocks = (E_EDGES + 2047) / 2048;   // 391
    int wave_grid   = (N_NODES + 3) / 4;

    // -------- CSR build --------
    hipMemsetAsync(bucketCnt, 0, NBUCK * sizeof(int), stream);
    bucket_count_kernel<<<edge_blocks, 256, 0, stream>>>(dst, bucketCnt, E_EDGES);
    bucket_scan_kernel<<<1, 128, 0, stream>>>(bucketCnt, bucketBase, bucketCursor);
    bucket_scatter_kernel<<<edge_blocks, 256, 0, stream>>>(src, dst, bucketCursor, pairs, E_EDGES);
    bucket_sort_kernel<<<NBUCK, 512, 0, stream>>>(pairs, bucketBase, offs, srcSorted, N_NODES, E_EDGES);

    // -------- weight prep (both layers) --------
    prep_all_kernel<<<258, 256, 0, stream>>>(
        W1_src, Wl1, W1_dst, att1_s, att1_d,
        W2_src, Wl2, W2_dst, att2_s, att2_d, Wt, Watt);

    // -------- layer 1 --------
    gemm_fused_kernel<0><<<ggrid, 256, 0, stream>>>(x, nullptr, Wt, Watt, bufbf, a_sd, N_NODES);
    aggregate_fused_kernel<0><<<wave_grid, 256, 0, stream>>>(
        srcSorted, offs, bufbf, a_sd, b1, bl1, gamma, beta, hbf, nullptr, N_NODES);

    // -------- layer 2 --------
    gemm_fused_kernel<1><<<ggrid, 256, 0, stream>>>(nullptr, hbf, Wt, Watt, bufbf, a_sd, N_NODES);
    aggregate_fused_kernel<1><<<wave_grid, 256, 0, stream>>>(
        srcSorted, offs, bufbf, a_sd, b2, bl2, nullptr, nullptr, nullptr, out, N_NODES);
}